// Round 2
// baseline (1625.626 us; speedup 1.0000x reference)
//
#include <hip/hip_runtime.h>
#include <cstdint>
#include <cstddef>

typedef unsigned short u16;
typedef __bf16 bf16x8 __attribute__((ext_vector_type(8)));
typedef float f32x4 __attribute__((ext_vector_type(4)));

#define B_ 2
#define L_ 4096
#define D_ 1024
#define N_ 16
#define BL_ 8192
#define NC_ 64   /* scan chunks */
#define LC_ 64   /* steps per chunk */

__device__ __forceinline__ float bf2f(u16 h) {
  union { unsigned int u; float f; } v; v.u = ((unsigned int)h) << 16; return v.f;
}
__device__ __forceinline__ u16 f2bf(float f) {
  union { float f; unsigned int u; } v; v.f = f;
  unsigned int r = v.u + 0x7FFFu + ((v.u >> 16) & 1u);
  return (u16)(r >> 16);
}
__device__ __forceinline__ float sigmoidf_(float x) { return 1.0f / (1.0f + __expf(-x)); }

// ---------------- GEMM: C[M,N] = A[M,K] @ W[N,K]^T ------------------------
// A: bf16 (u16, pre-rounded). W: fp32 (rounded to bf16 during staging).
#define BM 128
#define BN 128
#define BK 32
#define KST 40  // BK+8 pad: rows stay 16B-aligned; 2-way bank alias (free)

__global__ __launch_bounds__(256) void gemm_bt(
    const u16* __restrict__ A, const float* __restrict__ W, float* __restrict__ C,
    int M, int N, int K)
{
  __shared__ __align__(16) u16 As[BM * KST];
  __shared__ __align__(16) u16 Bs[BN * KST];
  const int bm = blockIdx.y * BM;
  const int bn = blockIdx.x * BN;
  const int tid = threadIdx.x;
  const int lane = tid & 63;
  const int wave = tid >> 6;
  const int wr = (wave >> 1) * 64;
  const int wc = (wave & 1) * 64;

  f32x4 acc[4][4];
#pragma unroll
  for (int i = 0; i < 4; ++i)
#pragma unroll
    for (int j = 0; j < 4; ++j)
#pragma unroll
      for (int r = 0; r < 4; ++r) acc[i][j][r] = 0.0f;

  for (int k0 = 0; k0 < K; k0 += BK) {
#pragma unroll
    for (int s = 0; s < 2; ++s) {
      int c = tid + s * 256;          // 512 chunks of 8 elements
      int row = c >> 2;
      int kc = (c & 3) << 3;
      uint4 va = {0u, 0u, 0u, 0u};
      if (bm + row < M) va = *(const uint4*)(A + (size_t)(bm + row) * K + (k0 + kc));
      *(uint4*)(&As[row * KST + kc]) = va;
      u16 wb[8];
      if (bn + row < N) {
        const float* wp = W + (size_t)(bn + row) * K + (k0 + kc);
#pragma unroll
        for (int e = 0; e < 8; ++e) wb[e] = f2bf(wp[e]);
      } else {
#pragma unroll
        for (int e = 0; e < 8; ++e) wb[e] = 0;
      }
      *(uint4*)(&Bs[row * KST + kc]) = *(const uint4*)wb;
    }
    __syncthreads();
    const int kq = (lane >> 4) << 3;  // k-offset of this lane-quad
    const int mr = lane & 15;
    bf16x8 af[4], bfr[4];
#pragma unroll
    for (int i = 0; i < 4; ++i)
      af[i] = *(const bf16x8*)(&As[(wr + i * 16 + mr) * KST + kq]);
#pragma unroll
    for (int j = 0; j < 4; ++j)
      bfr[j] = *(const bf16x8*)(&Bs[(wc + j * 16 + mr) * KST + kq]);
#pragma unroll
    for (int i = 0; i < 4; ++i)
#pragma unroll
      for (int j = 0; j < 4; ++j)
        acc[i][j] = __builtin_amdgcn_mfma_f32_16x16x32_bf16(af[i], bfr[j], acc[i][j], 0, 0, 0);
    __syncthreads();
  }

  const int mlo = (lane >> 4) << 2;   // C/D: row=(lane>>4)*4+r, col=lane&15 (m89)
  const int nlo = lane & 15;
#pragma unroll
  for (int i = 0; i < 4; ++i) {
#pragma unroll
    for (int j = 0; j < 4; ++j) {
      int col = bn + wc + j * 16 + nlo;
      if (col < N) {
#pragma unroll
        for (int r = 0; r < 4; ++r) {
          int row = bm + wr + i * 16 + mlo + r;
          if (row < M) C[(size_t)row * N + col] = acc[i][j][r];
        }
      }
    }
  }
}

// ---------------- LayerNorm helpers --------------------------------------
__device__ __forceinline__ void blockReduce2(float& s, float& q) {
#pragma unroll
  for (int o = 32; o > 0; o >>= 1) { s += __shfl_down(s, o, 64); q += __shfl_down(q, o, 64); }
  __shared__ float red[2][4];
  int lane = threadIdx.x & 63, wave = threadIdx.x >> 6;
  if (lane == 0) { red[0][wave] = s; red[1][wave] = q; }
  __syncthreads();
  s = red[0][0] + red[0][1] + red[0][2] + red[0][3];
  q = red[1][0] + red[1][1] + red[1][2] + red[1][3];
}

// LN over gathered fp32 row: out[b,l,:] = LN(x[b, path[l], :]) as bf16
__global__ __launch_bounds__(256) void ln_gather_k(
    const float* __restrict__ x, const int* __restrict__ path, u16* __restrict__ out)
{
  int b = blockIdx.x >> 12;
  int l = blockIdx.x & 4095;
  int src = path[l];
  const float* row = x + (((size_t)b * L_ + src) << 10);
  u16* orow = out + (((size_t)b * L_ + l) << 10);
  float v[4], s = 0.f, q = 0.f;
#pragma unroll
  for (int i = 0; i < 4; ++i) {
    v[i] = row[threadIdx.x + (i << 8)];
    s += v[i]; q += v[i] * v[i];
  }
  blockReduce2(s, q);
  float mean = s * (1.0f / 1024.0f);
  float var = q * (1.0f / 1024.0f) - mean * mean;
  float rstd = rsqrtf(var + 1e-6f);
#pragma unroll
  for (int i = 0; i < 4; ++i)
    orow[threadIdx.x + (i << 8)] = f2bf((v[i] - mean) * rstd);
}

// LN over fp32 row -> bf16
__global__ __launch_bounds__(256) void ln_f32_k(
    const float* __restrict__ xin, u16* __restrict__ out)
{
  size_t base = ((size_t)blockIdx.x) << 10;
  float v[4], s = 0.f, q = 0.f;
#pragma unroll
  for (int i = 0; i < 4; ++i) {
    v[i] = xin[base + threadIdx.x + (i << 8)];
    s += v[i]; q += v[i] * v[i];
  }
  blockReduce2(s, q);
  float mean = s * (1.0f / 1024.0f);
  float var = q * (1.0f / 1024.0f) - mean * mean;
  float rstd = rsqrtf(var + 1e-6f);
#pragma unroll
  for (int i = 0; i < 4; ++i)
    out[base + threadIdx.x + (i << 8)] = f2bf((v[i] - mean) * rstd);
}

// ---------------- conv1d(4, causal) + SiLU; xi = xz[:, :1024] -------------
__global__ __launch_bounds__(256) void conv_silu_k(
    const float* __restrict__ xz, const float* __restrict__ cw, const float* __restrict__ cb,
    u16* __restrict__ xc)
{
  int idx = blockIdx.x * 256 + threadIdx.x;  // B*L*Di
  int d = idx & 1023;
  int l = (idx >> 10) & 4095;
  int b = idx >> 22;
  float acc = cb[d];
#pragma unroll
  for (int k = 0; k < 4; ++k) {
    int ls = l + k - 3;
    if (ls >= 0)
      acc += cw[(d << 2) + k] * xz[(((size_t)b * L_ + ls) << 11) + d];
  }
  acc = acc * sigmoidf_(acc);
  xc[idx] = f2bf(acc);
}

__global__ void extract_dtr_k(const float* __restrict__ proj, u16* __restrict__ dtr) {
  int idx = blockIdx.x * 256 + threadIdx.x;  // BL*64
  int m = idx >> 6, r = idx & 63;
  dtr[idx] = f2bf(proj[m * 96 + r]);
}

__global__ void softplus_k(float* __restrict__ dt, const float* __restrict__ dtb) {
  int idx = blockIdx.x * 256 + threadIdx.x;  // BL*1024
  float v = dt[idx] + dtb[idx & 1023];
  dt[idx] = (v > 20.0f) ? v : log1pf(__expf(v));
}

// ---------------- selective scan, 3-phase chunked -------------------------
// state layout: [(b*1024+d)*NC + c]*16 + n
__global__ __launch_bounds__(256) void scan_p1_k(
    const float* __restrict__ dt, const u16* __restrict__ xc, const float* __restrict__ proj,
    const float* __restrict__ A_log, float* __restrict__ acum, float* __restrict__ hloc)
{
  int c = blockIdx.x & (NC_ - 1);
  int q = (blockIdx.x >> 6) & 3;
  int b = blockIdx.x >> 8;
  int d = (q << 8) + threadIdx.x;
  float Arow[N_];
#pragma unroll
  for (int n = 0; n < N_; ++n) Arow[n] = -__expf(A_log[(d << 4) + n]);
  float h[N_], ac[N_];
#pragma unroll
  for (int n = 0; n < N_; ++n) { h[n] = 0.0f; ac[n] = 1.0f; }
  int l0 = c << 6;
  for (int i = 0; i < LC_; ++i) {
    size_t rowb = (size_t)b * L_ + (l0 + i);
    float dtv = dt[(rowb << 10) + d];
    float xv = bf2f(xc[(rowb << 10) + d]);
    float dtx = dtv * xv;
    const float* Bp = proj + rowb * 96 + 64;
#pragma unroll
    for (int n = 0; n < N_; ++n) {
      float dA = __expf(dtv * Arow[n]);
      h[n] = dA * h[n] + dtx * Bp[n];
      ac[n] *= dA;
    }
  }
  size_t sb = ((((size_t)b << 10) + d) << 10) + (c << 4);
#pragma unroll
  for (int n = 0; n < N_; ++n) { acum[sb + n] = ac[n]; hloc[sb + n] = h[n]; }
}

__global__ __launch_bounds__(256) void scan_p2_k(
    const float* __restrict__ acum, const float* __restrict__ hloc, float* __restrict__ hin)
{
  int idx = blockIdx.x * 256 + threadIdx.x;  // B*1024*16
  int n = idx & 15;
  int dn = idx >> 4;
  size_t base = ((size_t)dn << 10) + n;
  float hs = 0.0f;
  for (int c = 0; c < NC_; ++c) {
    hin[base + (c << 4)] = hs;
    hs = acum[base + (c << 4)] * hs + hloc[base + (c << 4)];
  }
}

// phase 3: replay with true h_in; fuse y = scan + D*xc, gate *= silu(z), -> bf16
__global__ __launch_bounds__(256) void scan_p3_k(
    const float* __restrict__ dt, const u16* __restrict__ xc, const float* __restrict__ proj,
    const float* __restrict__ A_log, const float* __restrict__ Dp, const float* __restrict__ hin,
    const float* __restrict__ xz, u16* __restrict__ yg)
{
  int c = blockIdx.x & (NC_ - 1);
  int q = (blockIdx.x >> 6) & 3;
  int b = blockIdx.x >> 8;
  int d = (q << 8) + threadIdx.x;
  float Arow[N_];
#pragma unroll
  for (int n = 0; n < N_; ++n) Arow[n] = -__expf(A_log[(d << 4) + n]);
  float h[N_];
  size_t sb = ((((size_t)b << 10) + d) << 10) + (c << 4);
#pragma unroll
  for (int n = 0; n < N_; ++n) h[n] = hin[sb + n];
  float Dv = Dp[d];
  int l0 = c << 6;
  for (int i = 0; i < LC_; ++i) {
    size_t rowb = (size_t)b * L_ + (l0 + i);
    float dtv = dt[(rowb << 10) + d];
    float xv = bf2f(xc[(rowb << 10) + d]);
    float dtx = dtv * xv;
    const float* Bp = proj + rowb * 96 + 64;
    const float* Cp = proj + rowb * 96 + 80;
    float y = 0.0f;
#pragma unroll
    for (int n = 0; n < N_; ++n) {
      float dA = __expf(dtv * Arow[n]);
      h[n] = dA * h[n] + dtx * Bp[n];
      y += h[n] * Cp[n];
    }
    y += Dv * xv;
    float zv = xz[(rowb << 11) + 1024 + d];
    yg[(rowb << 10) + d] = f2bf(y * zv * sigmoidf_(zv));
  }
}

// x_new[b,l,:] = x[b,l,:] + mo[b, path_rev[l], :]
__global__ void scatter_res_k(const float* __restrict__ x, const int* __restrict__ prev,
                              const float* __restrict__ mo, float* __restrict__ xnew)
{
  int idx = blockIdx.x * 256 + threadIdx.x;  // B*L*D
  int d = idx & 1023;
  int l = (idx >> 10) & 4095;
  int b = idx >> 22;
  int pl = prev[l];
  xnew[idx] = x[idx] + mo[(((size_t)b * L_ + pl) << 10) + d];
}

__global__ void gelu_k(const float* __restrict__ h1, const float* __restrict__ b1,
                       u16* __restrict__ h1b)
{
  int idx = blockIdx.x * 256 + threadIdx.x;  // Mc*4096
  float v = h1[idx] + b1[idx & 4095];
  float a = 0.7978845608028654f * (v + 0.044715f * v * v * v);
  float t = 1.0f - 2.0f / (__expf(2.0f * a) + 1.0f);   // tanh(a)
  h1b[idx] = f2bf(0.5f * v * (1.0f + t));
}

__global__ void addout_k(const float* __restrict__ xnew, const float* __restrict__ h2,
                         const float* __restrict__ b2, float* __restrict__ out)
{
  int idx = blockIdx.x * 256 + threadIdx.x;  // Mc*1024
  out[idx] = xnew[idx] + h2[idx] + b2[idx & 1023];
}

// ---------------- driver ---------------------------------------------------
extern "C" void kernel_launch(void* const* d_in, const int* in_sizes, int n_in,
                              void* d_out, int out_size, void* d_ws, size_t ws_size,
                              hipStream_t stream)
{
  const float* x_in      = (const float*)d_in[0];
  const int*   path      = (const int*)d_in[1];
  const int*   path_rev  = (const int*)d_in[2];
  const float* in_proj_w = (const float*)d_in[3];
  const float* conv_w    = (const float*)d_in[4];
  const float* conv_b    = (const float*)d_in[5];
  const float* x_proj_w  = (const float*)d_in[6];
  const float* dt_proj_w = (const float*)d_in[7];
  const float* dt_proj_b = (const float*)d_in[8];
  const float* A_log     = (const float*)d_in[9];
  const float* Dp        = (const float*)d_in[10];
  const float* out_pw    = (const float*)d_in[11];
  const float* fc1_w     = (const float*)d_in[12];
  const float* fc1_b     = (const float*)d_in[13];
  const float* fc2_w     = (const float*)d_in[14];
  const float* fc2_b     = (const float*)d_in[15];
  float* out = (float*)d_out;

  char* w = (char*)d_ws;
  size_t off = 0;
  auto alloc = [&](size_t bytes) -> char* {
    char* p = w + off;
    off = (off + bytes + 255) & ~(size_t)255;
    return p;
  };
  u16*   ln_bf = (u16*)  alloc((size_t)BL_ * 1024 * 2);  // LN1 out; later LN2 out
  float* xz    = (float*)alloc((size_t)BL_ * 2048 * 4);  // later: mo | xnew; then h1 | xnew
  u16*   xc    = (u16*)  alloc((size_t)BL_ * 1024 * 2);
  float* proj  = (float*)alloc((size_t)BL_ * 96 * 4);
  u16*   dtr   = (u16*)  alloc((size_t)BL_ * 64 * 2);
  float* dt    = (float*)alloc((size_t)BL_ * 1024 * 4);  // later: h1b (bf16 chunk)
  float* acum  = (float*)alloc((size_t)2 * 1024 * NC_ * 16 * 4);  // later: h2 chunk
  float* hloc  = (float*)alloc((size_t)2 * 1024 * NC_ * 16 * 4);
  float* hin   = (float*)alloc((size_t)2 * 1024 * NC_ * 16 * 4);
  u16*   yg    = (u16*)  alloc((size_t)BL_ * 1024 * 2);
  float* mo    = xz;                                           // alias (z dead after p3)
  float* xnew  = (float*)((char*)xz + (size_t)BL_ * 1024 * 4); // alias, upper half
  float* h1    = xz;                                           // alias (mo dead after scatter)
  u16*   h1b   = (u16*)dt;
  float* h2    = acum;

  dim3 blk(256);
  ln_gather_k<<<BL_, blk, 0, stream>>>(x_in, path, ln_bf);
  gemm_bt<<<dim3(16, 64), blk, 0, stream>>>(ln_bf, in_proj_w, xz, 8192, 2048, 1024);
  conv_silu_k<<<(BL_ * 1024) / 256, blk, 0, stream>>>(xz, conv_w, conv_b, xc);
  gemm_bt<<<dim3(1, 64), blk, 0, stream>>>(xc, x_proj_w, proj, 8192, 96, 1024);
  extract_dtr_k<<<(BL_ * 64) / 256, blk, 0, stream>>>(proj, dtr);
  gemm_bt<<<dim3(8, 64), blk, 0, stream>>>(dtr, dt_proj_w, dt, 8192, 1024, 64);
  softplus_k<<<(BL_ * 1024) / 256, blk, 0, stream>>>(dt, dt_proj_b);
  scan_p1_k<<<2 * 4 * NC_, blk, 0, stream>>>(dt, xc, proj, A_log, acum, hloc);
  scan_p2_k<<<(2 * 1024 * 16) / 256, blk, 0, stream>>>(acum, hloc, hin);
  scan_p3_k<<<2 * 4 * NC_, blk, 0, stream>>>(dt, xc, proj, A_log, Dp, hin, xz, yg);
  gemm_bt<<<dim3(8, 64), blk, 0, stream>>>(yg, out_pw, mo, 8192, 1024, 1024);
  scatter_res_k<<<(BL_ * 1024) / 256, blk, 0, stream>>>(x_in, path_rev, mo, xnew);
  ln_f32_k<<<BL_, blk, 0, stream>>>(xnew, ln_bf);
  for (int r = 0; r < 4; ++r) {
    const u16* a2 = ln_bf + (size_t)r * 2048 * 1024;
    gemm_bt<<<dim3(32, 16), blk, 0, stream>>>(a2, fc1_w, h1, 2048, 4096, 1024);
    gelu_k<<<(2048 * 4096) / 256, blk, 0, stream>>>(h1, fc1_b, h1b);
    gemm_bt<<<dim3(8, 16), blk, 0, stream>>>(h1b, fc2_w, h2, 2048, 1024, 4096);
    addout_k<<<(2048 * 1024) / 256, blk, 0, stream>>>(
        xnew + (size_t)r * 2048 * 1024, h2, fc2_b, out + (size_t)r * 2048 * 1024);
  }
}

// Round 3
// 682.051 us; speedup vs baseline: 2.3834x; 2.3834x over previous
//
#include <hip/hip_runtime.h>
#include <cstdint>
#include <cstddef>

typedef unsigned short u16;
typedef __bf16 bf16x8 __attribute__((ext_vector_type(8)));
typedef float f32x4 __attribute__((ext_vector_type(4)));

#define B_ 2
#define L_ 4096
#define D_ 1024
#define N_ 16
#define BL_ 8192
#define NC_ 64   /* scan chunks */
#define LC_ 64   /* steps per chunk */

__device__ __forceinline__ float bf2f(u16 h) {
  union { unsigned int u; float f; } v; v.u = ((unsigned int)h) << 16; return v.f;
}
__device__ __forceinline__ u16 f2bf(float f) {
  union { float f; unsigned int u; } v; v.f = f;
  unsigned int r = v.u + 0x7FFFu + ((v.u >> 16) & 1u);
  return (u16)(r >> 16);
}
__device__ __forceinline__ float sigmoidf_(float x) { return 1.0f / (1.0f + __expf(-x)); }

// ---- weight fp32->bf16 pre-conversion (x_proj padded to 128 rows) --------
// dst element offsets:
//  in_proj [0,2097152) | x_proj [2097152,2228224) (src 98304, rest 0)
//  dt_proj [2228224,2293760) | out_pw [2293760,3342336)
//  fc1 [3342336,7536640) | fc2 [7536640,11730944)
#define WBF_TOT 11730944
__global__ __launch_bounds__(256) void cvt_w_k(
    const float* __restrict__ s0, const float* __restrict__ s1,
    const float* __restrict__ s2, const float* __restrict__ s3,
    const float* __restrict__ s4, const float* __restrict__ s5,
    u16* __restrict__ dst)
{
  int i = blockIdx.x * 256 + threadIdx.x;
  if (i >= WBF_TOT) return;
  float v;
  if (i < 2097152) v = s0[i];
  else if (i < 2228224) { int j = i - 2097152; v = (j < 98304) ? s1[j] : 0.0f; }
  else if (i < 2293760) v = s2[i - 2228224];
  else if (i < 3342336) v = s3[i - 2293760];
  else if (i < 7536640) v = s4[i - 3342336];
  else v = s5[i - 7536640];
  dst[i] = f2bf(v);
}

// ---------------- GEMM: C = A[M,K] @ W[N,K]^T, both bf16, m97 structure ----
#define BM 128
#define BN 128
#define BK 32

enum { M_NONE = 0, M_PROJ = 1, M_SOFTPLUS = 2, M_GELU = 3, M_BIASRES = 4 };

template<int MODE>
__global__ __launch_bounds__(256) void gemm_bt(
    const u16* __restrict__ A, const u16* __restrict__ W,
    float* __restrict__ C, u16* __restrict__ C2,
    const float* __restrict__ bias, const float* __restrict__ resid,
    int M, int N, int K)
{
  __shared__ __align__(16) u16 As[BM * BK];
  __shared__ __align__(16) u16 Bs[BN * BK];
  const int bm = blockIdx.y * BM;
  const int bn = blockIdx.x * BN;
  const int tid = threadIdx.x;
  const int lane = tid & 63;
  const int wave = tid >> 6;
  const int wr = (wave >> 1) * 64;
  const int wc = (wave & 1) * 64;

  f32x4 acc[4][4];
#pragma unroll
  for (int i = 0; i < 4; ++i)
#pragma unroll
    for (int j = 0; j < 4; ++j)
#pragma unroll
      for (int r = 0; r < 4; ++r) acc[i][j][r] = 0.0f;

  // staging map: chunk c in [0,512): LDS byte off c*16; row=c>>2, kelem=(c&3)*8
  const int r0 = tid >> 2;            // chunk c = tid   -> row
  const int r1 = (tid + 256) >> 2;    // chunk c = tid+256
  const int ke = (tid & 3) << 3;

  for (int k0 = 0; k0 < K; k0 += BK) {
    __builtin_amdgcn_global_load_lds(
        (const __attribute__((address_space(1))) void*)(A + (size_t)(bm + r0) * K + k0 + ke),
        (__attribute__((address_space(3))) void*)(&As[(size_t)tid * 8]), 16, 0, 0);
    __builtin_amdgcn_global_load_lds(
        (const __attribute__((address_space(1))) void*)(A + (size_t)(bm + r1) * K + k0 + ke),
        (__attribute__((address_space(3))) void*)(&As[(size_t)(tid + 256) * 8]), 16, 0, 0);
    __builtin_amdgcn_global_load_lds(
        (const __attribute__((address_space(1))) void*)(W + (size_t)(bn + r0) * K + k0 + ke),
        (__attribute__((address_space(3))) void*)(&Bs[(size_t)tid * 8]), 16, 0, 0);
    __builtin_amdgcn_global_load_lds(
        (const __attribute__((address_space(1))) void*)(W + (size_t)(bn + r1) * K + k0 + ke),
        (__attribute__((address_space(3))) void*)(&Bs[(size_t)(tid + 256) * 8]), 16, 0, 0);
    __syncthreads();
    const int kq = (lane >> 4) << 3;
    const int mr = lane & 15;
    bf16x8 af[4], bfr[4];
#pragma unroll
    for (int i = 0; i < 4; ++i)
      af[i] = *(const bf16x8*)(&As[(wr + i * 16 + mr) * BK + kq]);
#pragma unroll
    for (int j = 0; j < 4; ++j)
      bfr[j] = *(const bf16x8*)(&Bs[(wc + j * 16 + mr) * BK + kq]);
#pragma unroll
    for (int i = 0; i < 4; ++i)
#pragma unroll
      for (int j = 0; j < 4; ++j)
        acc[i][j] = __builtin_amdgcn_mfma_f32_16x16x32_bf16(af[i], bfr[j], acc[i][j], 0, 0, 0);
    __syncthreads();
  }

  const int mlo = (lane >> 4) << 2;   // C/D: row=(lane>>4)*4+r, col=lane&15 (m89)
  const int nlo = lane & 15;
#pragma unroll
  for (int i = 0; i < 4; ++i) {
#pragma unroll
    for (int j = 0; j < 4; ++j) {
      int col = bn + wc + j * 16 + nlo;
      if (col < N) {
#pragma unroll
        for (int r = 0; r < 4; ++r) {
          int row = bm + wr + i * 16 + mlo + r;
          float v = acc[i][j][r];
          if constexpr (MODE == M_NONE) {
            C[(size_t)row * N + col] = v;
          } else if constexpr (MODE == M_PROJ) {
            C[(size_t)row * N + col] = v;
            if (col < 64) C2[((size_t)row << 6) + col] = f2bf(v);
          } else if constexpr (MODE == M_SOFTPLUS) {
            v += bias[col];
            C[(size_t)row * N + col] = (v > 20.0f) ? v : log1pf(__expf(v));
          } else if constexpr (MODE == M_GELU) {
            v += bias[col];
            float a = 0.7978845608028654f * (v + 0.044715f * v * v * v);
            float t = 1.0f - 2.0f / (__expf(2.0f * a) + 1.0f);
            C2[(size_t)row * N + col] = f2bf(0.5f * v * (1.0f + t));
          } else if constexpr (MODE == M_BIASRES) {
            C[(size_t)row * N + col] = v + bias[col] + resid[(size_t)row * N + col];
          }
        }
      }
    }
  }
}

// ---------------- LayerNorm helpers --------------------------------------
__device__ __forceinline__ void blockReduce2(float& s, float& q) {
#pragma unroll
  for (int o = 32; o > 0; o >>= 1) { s += __shfl_down(s, o, 64); q += __shfl_down(q, o, 64); }
  __shared__ float red[2][4];
  int lane = threadIdx.x & 63, wave = threadIdx.x >> 6;
  if (lane == 0) { red[0][wave] = s; red[1][wave] = q; }
  __syncthreads();
  s = red[0][0] + red[0][1] + red[0][2] + red[0][3];
  q = red[1][0] + red[1][1] + red[1][2] + red[1][3];
}

// out[b,l,:] = LN(x[b, path[l], :]) as bf16
__global__ __launch_bounds__(256) void ln_gather_k(
    const float* __restrict__ x, const int* __restrict__ path, u16* __restrict__ out)
{
  int b = blockIdx.x >> 12;
  int l = blockIdx.x & 4095;
  int src = path[l];
  const float* row = x + (((size_t)b * L_ + src) << 10);
  u16* orow = out + (((size_t)b * L_ + l) << 10);
  float v[4], s = 0.f, q = 0.f;
#pragma unroll
  for (int i = 0; i < 4; ++i) {
    v[i] = row[threadIdx.x + (i << 8)];
    s += v[i]; q += v[i] * v[i];
  }
  blockReduce2(s, q);
  float mean = s * (1.0f / 1024.0f);
  float var = q * (1.0f / 1024.0f) - mean * mean;
  float rstd = rsqrtf(var + 1e-6f);
#pragma unroll
  for (int i = 0; i < 4; ++i)
    orow[threadIdx.x + (i << 8)] = f2bf((v[i] - mean) * rstd);
}

// xnew = x + mo[b, prev[l], :]; lnout = LN(xnew) bf16  (fused scatter+LN2)
__global__ __launch_bounds__(256) void ln_scatter_k(
    const float* __restrict__ x, const int* __restrict__ prev,
    const float* __restrict__ mo, float* __restrict__ xnew, u16* __restrict__ lnout)
{
  int b = blockIdx.x >> 12;
  int l = blockIdx.x & 4095;
  int pl = prev[l];
  const float* xr = x + (((size_t)b * L_ + l) << 10);
  const float* mr_ = mo + (((size_t)b * L_ + pl) << 10);
  size_t base = ((size_t)blockIdx.x) << 10;
  float v[4], s = 0.f, q = 0.f;
#pragma unroll
  for (int i = 0; i < 4; ++i) {
    v[i] = xr[threadIdx.x + (i << 8)] + mr_[threadIdx.x + (i << 8)];
    s += v[i]; q += v[i] * v[i];
  }
  blockReduce2(s, q);
  float mean = s * (1.0f / 1024.0f);
  float var = q * (1.0f / 1024.0f) - mean * mean;
  float rstd = rsqrtf(var + 1e-6f);
#pragma unroll
  for (int i = 0; i < 4; ++i) {
    xnew[base + threadIdx.x + (i << 8)] = v[i];
    lnout[base + threadIdx.x + (i << 8)] = f2bf((v[i] - mean) * rstd);
  }
}

// ---------------- conv1d(4, causal) + SiLU; xi = xz[:, :1024] -------------
__global__ __launch_bounds__(256) void conv_silu_k(
    const float* __restrict__ xz, const float* __restrict__ cw, const float* __restrict__ cb,
    u16* __restrict__ xc)
{
  int idx = blockIdx.x * 256 + threadIdx.x;  // B*L*Di
  int d = idx & 1023;
  int l = (idx >> 10) & 4095;
  int b = idx >> 22;
  float acc = cb[d];
#pragma unroll
  for (int k = 0; k < 4; ++k) {
    int ls = l + k - 3;
    if (ls >= 0)
      acc += cw[(d << 2) + k] * xz[(((size_t)b * L_ + ls) << 11) + d];
  }
  acc = acc * sigmoidf_(acc);
  xc[idx] = f2bf(acc);
}

// ---------------- selective scan, 3-phase chunked -------------------------
__global__ __launch_bounds__(256) void scan_p1_k(
    const float* __restrict__ dt, const u16* __restrict__ xc, const float* __restrict__ proj,
    const float* __restrict__ A_log, float* __restrict__ acum, float* __restrict__ hloc)
{
  int c = blockIdx.x & (NC_ - 1);
  int q = (blockIdx.x >> 6) & 3;
  int b = blockIdx.x >> 8;
  int d = (q << 8) + threadIdx.x;
  float Arow[N_];
#pragma unroll
  for (int n = 0; n < N_; ++n) Arow[n] = -__expf(A_log[(d << 4) + n]);
  float h[N_], ac[N_];
#pragma unroll
  for (int n = 0; n < N_; ++n) { h[n] = 0.0f; ac[n] = 1.0f; }
  int l0 = c << 6;
  for (int i = 0; i < LC_; ++i) {
    size_t rowb = (size_t)b * L_ + (l0 + i);
    float dtv = dt[(rowb << 10) + d];
    float xv = bf2f(xc[(rowb << 10) + d]);
    float dtx = dtv * xv;
    const float* Bp = proj + rowb * 96 + 64;
#pragma unroll
    for (int n = 0; n < N_; ++n) {
      float dA = __expf(dtv * Arow[n]);
      h[n] = dA * h[n] + dtx * Bp[n];
      ac[n] *= dA;
    }
  }
  size_t sb = ((((size_t)b << 10) + d) << 10) + (c << 4);
#pragma unroll
  for (int n = 0; n < N_; ++n) { acum[sb + n] = ac[n]; hloc[sb + n] = h[n]; }
}

__global__ __launch_bounds__(256) void scan_p2_k(
    const float* __restrict__ acum, const float* __restrict__ hloc, float* __restrict__ hin)
{
  int idx = blockIdx.x * 256 + threadIdx.x;  // B*1024*16
  int n = idx & 15;
  int dn = idx >> 4;
  size_t base = ((size_t)dn << 10) + n;
  float hs = 0.0f;
  for (int c = 0; c < NC_; ++c) {
    hin[base + (c << 4)] = hs;
    hs = acum[base + (c << 4)] * hs + hloc[base + (c << 4)];
  }
}

__global__ __launch_bounds__(256) void scan_p3_k(
    const float* __restrict__ dt, const u16* __restrict__ xc, const float* __restrict__ proj,
    const float* __restrict__ A_log, const float* __restrict__ Dp, const float* __restrict__ hin,
    const float* __restrict__ xz, u16* __restrict__ yg)
{
  int c = blockIdx.x & (NC_ - 1);
  int q = (blockIdx.x >> 6) & 3;
  int b = blockIdx.x >> 8;
  int d = (q << 8) + threadIdx.x;
  float Arow[N_];
#pragma unroll
  for (int n = 0; n < N_; ++n) Arow[n] = -__expf(A_log[(d << 4) + n]);
  float h[N_];
  size_t sb = ((((size_t)b << 10) + d) << 10) + (c << 4);
#pragma unroll
  for (int n = 0; n < N_; ++n) h[n] = hin[sb + n];
  float Dv = Dp[d];
  int l0 = c << 6;
  for (int i = 0; i < LC_; ++i) {
    size_t rowb = (size_t)b * L_ + (l0 + i);
    float dtv = dt[(rowb << 10) + d];
    float xv = bf2f(xc[(rowb << 10) + d]);
    float dtx = dtv * xv;
    const float* Bp = proj + rowb * 96 + 64;
    const float* Cp = proj + rowb * 96 + 80;
    float y = 0.0f;
#pragma unroll
    for (int n = 0; n < N_; ++n) {
      float dA = __expf(dtv * Arow[n]);
      h[n] = dA * h[n] + dtx * Bp[n];
      y += h[n] * Cp[n];
    }
    y += Dv * xv;
    float zv = xz[(rowb << 11) + 1024 + d];
    yg[(rowb << 10) + d] = f2bf(y * zv * sigmoidf_(zv));
  }
}

// ---------------- driver ---------------------------------------------------
extern "C" void kernel_launch(void* const* d_in, const int* in_sizes, int n_in,
                              void* d_out, int out_size, void* d_ws, size_t ws_size,
                              hipStream_t stream)
{
  const float* x_in      = (const float*)d_in[0];
  const int*   path      = (const int*)d_in[1];
  const int*   path_rev  = (const int*)d_in[2];
  const float* in_proj_w = (const float*)d_in[3];
  const float* conv_w    = (const float*)d_in[4];
  const float* conv_b    = (const float*)d_in[5];
  const float* x_proj_w  = (const float*)d_in[6];
  const float* dt_proj_w = (const float*)d_in[7];
  const float* dt_proj_b = (const float*)d_in[8];
  const float* A_log     = (const float*)d_in[9];
  const float* Dp        = (const float*)d_in[10];
  const float* out_pw    = (const float*)d_in[11];
  const float* fc1_w     = (const float*)d_in[12];
  const float* fc1_b     = (const float*)d_in[13];
  const float* fc2_w     = (const float*)d_in[14];
  const float* fc2_b     = (const float*)d_in[15];
  float* out = (float*)d_out;

  char* w = (char*)d_ws;
  size_t off = 0;
  auto alloc = [&](size_t bytes) -> char* {
    char* p = w + off;
    off = (off + bytes + 255) & ~(size_t)255;
    return p;
  };
  u16*   wbf   = (u16*)  alloc((size_t)WBF_TOT * 2);     // bf16 weights
  u16*   ln_bf = (u16*)  alloc((size_t)BL_ * 1024 * 2);  // LN1 out; later LN2 out
  float* xz    = (float*)alloc((size_t)BL_ * 2048 * 4);  // later: mo (lower) | xnew (upper)
  u16*   xc    = (u16*)  alloc((size_t)BL_ * 1024 * 2);
  char*  pool0 = alloc(0);
  float* proj  = (float*)alloc((size_t)BL_ * 96 * 4);
  u16*   dtr   = (u16*)  alloc((size_t)BL_ * 64 * 2);
  float* dt    = (float*)alloc((size_t)BL_ * 1024 * 4);
  float* acum  = (float*)alloc((size_t)2 * 1024 * NC_ * 16 * 4);
  float* hloc  = (float*)alloc((size_t)2 * 1024 * NC_ * 16 * 4);
  float* hin   = (float*)alloc((size_t)2 * 1024 * NC_ * 16 * 4);
  u16*   yg    = (u16*)  alloc((size_t)BL_ * 1024 * 2);
  float* mo    = xz;                                           // alias (z dead after p3)
  float* xnew  = (float*)((char*)xz + (size_t)BL_ * 1024 * 4); // alias, upper half
  u16*   h1b   = (u16*)pool0;   // 64 MB; pool (proj..yg = 76 MB) dead by fc1

  const u16* w_inp = wbf;
  const u16* w_xp  = wbf + 2097152;
  const u16* w_dtp = wbf + 2228224;
  const u16* w_op  = wbf + 2293760;
  const u16* w_fc1 = wbf + 3342336;
  const u16* w_fc2 = wbf + 7536640;

  dim3 blk(256);
  cvt_w_k<<<WBF_TOT / 256, blk, 0, stream>>>(in_proj_w, x_proj_w, dt_proj_w, out_pw,
                                             fc1_w, fc2_w, wbf);
  ln_gather_k<<<BL_, blk, 0, stream>>>(x_in, path, ln_bf);
  gemm_bt<M_NONE><<<dim3(16, 64), blk, 0, stream>>>(ln_bf, w_inp, xz, nullptr, nullptr, nullptr, 8192, 2048, 1024);
  conv_silu_k<<<(BL_ * 1024) / 256, blk, 0, stream>>>(xz, conv_w, conv_b, xc);
  gemm_bt<M_PROJ><<<dim3(1, 64), blk, 0, stream>>>(xc, w_xp, proj, dtr, nullptr, nullptr, 8192, 96, 1024);
  gemm_bt<M_SOFTPLUS><<<dim3(8, 64), blk, 0, stream>>>(dtr, w_dtp, dt, nullptr, dt_proj_b, nullptr, 8192, 1024, 64);
  scan_p1_k<<<2 * 4 * NC_, blk, 0, stream>>>(dt, xc, proj, A_log, acum, hloc);
  scan_p2_k<<<(2 * 1024 * 16) / 256, blk, 0, stream>>>(acum, hloc, hin);
  scan_p3_k<<<2 * 4 * NC_, blk, 0, stream>>>(dt, xc, proj, A_log, Dp, hin, xz, yg);
  gemm_bt<M_NONE><<<dim3(8, 64), blk, 0, stream>>>(yg, w_op, mo, nullptr, nullptr, nullptr, 8192, 1024, 1024);
  ln_scatter_k<<<BL_, blk, 0, stream>>>(x_in, path_rev, mo, xnew, ln_bf);
  gemm_bt<M_GELU><<<dim3(32, 64), blk, 0, stream>>>(ln_bf, w_fc1, nullptr, h1b, fc1_b, nullptr, 8192, 4096, 1024);
  gemm_bt<M_BIASRES><<<dim3(8, 64), blk, 0, stream>>>(h1b, w_fc2, out, nullptr, fc2_b, xnew, 8192, 1024, 4096);
}

// Round 4
// 638.152 us; speedup vs baseline: 2.5474x; 1.0688x over previous
//
#include <hip/hip_runtime.h>
#include <cstdint>
#include <cstddef>

typedef unsigned short u16;
typedef __bf16 bf16x8 __attribute__((ext_vector_type(8)));
typedef float f32x4 __attribute__((ext_vector_type(4)));

#define B_ 2
#define L_ 4096
#define D_ 1024
#define N_ 16
#define BL_ 8192
#define NC_ 64   /* scan chunks */
#define LC_ 64   /* steps per chunk */

__device__ __forceinline__ float bf2f(u16 h) {
  union { unsigned int u; float f; } v; v.u = ((unsigned int)h) << 16; return v.f;
}
__device__ __forceinline__ u16 f2bf(float f) {
  union { float f; unsigned int u; } v; v.f = f;
  unsigned int r = v.u + 0x7FFFu + ((v.u >> 16) & 1u);
  return (u16)(r >> 16);
}
__device__ __forceinline__ float sigmoidf_(float x) { return 1.0f / (1.0f + __expf(-x)); }

// ---- weight fp32->bf16 pre-conversion (x_proj padded to 128 rows) --------
#define WBF_TOT 11730944
__global__ __launch_bounds__(256) void cvt_w_k(
    const float* __restrict__ s0, const float* __restrict__ s1,
    const float* __restrict__ s2, const float* __restrict__ s3,
    const float* __restrict__ s4, const float* __restrict__ s5,
    u16* __restrict__ dst)
{
  int i = blockIdx.x * 256 + threadIdx.x;
  if (i >= WBF_TOT) return;
  float v;
  if (i < 2097152) v = s0[i];
  else if (i < 2228224) { int j = i - 2097152; v = (j < 98304) ? s1[j] : 0.0f; }
  else if (i < 2293760) v = s2[i - 2228224];
  else if (i < 3342336) v = s3[i - 2293760];
  else if (i < 7536640) v = s4[i - 3342336];
  else v = s5[i - 7536640];
  dst[i] = f2bf(v);
}

// ---------------- GEMM: C = A[M,K] @ W[N,K]^T, both bf16 -------------------
// Double-buffered LDS (loads issued post-barrier overlap the MFMA phase),
// XCD-aware block swizzle (id%8 = XCD; each XCD owns an 8-tile M-band).
#define BM 128
#define BN 128
#define BK 32

enum { M_BF16 = 0, M_PROJ = 1, M_SOFTPLUS = 2, M_GELU = 3, M_BIASRES = 4 };

#define GLDS(gp, lp) __builtin_amdgcn_global_load_lds( \
    (const __attribute__((address_space(1))) void*)(gp), \
    (__attribute__((address_space(3))) void*)(lp), 16, 0, 0)

template<int MODE>
__global__ __launch_bounds__(256) void gemm_bt(
    const u16* __restrict__ A, const u16* __restrict__ W,
    float* __restrict__ C, u16* __restrict__ C2,
    const float* __restrict__ bias, const float* __restrict__ resid,
    int M, int N, int K)
{
  __shared__ __align__(16) u16 As[2][BM * BK];
  __shared__ __align__(16) u16 Bs[2][BN * BK];

  // XCD swizzle: grid y is always a multiple of 8 here.
  const int id = blockIdx.x + gridDim.x * blockIdx.y;
  const int xcd = id & 7;
  const int q = id >> 3;
  const int bandH = gridDim.y >> 3;
  const int xs = q % gridDim.x;
  const int ys = xcd * bandH + q / gridDim.x;
  const int bm = ys * BM;
  const int bn = xs * BN;

  const int tid = threadIdx.x;
  const int lane = tid & 63;
  const int wave = tid >> 6;
  const int wr = (wave >> 1) * 64;
  const int wc = (wave & 1) * 64;

  f32x4 acc[4][4];
#pragma unroll
  for (int i = 0; i < 4; ++i)
#pragma unroll
    for (int j = 0; j < 4; ++j)
#pragma unroll
      for (int r = 0; r < 4; ++r) acc[i][j][r] = 0.0f;

  // staging: 512 chunks of 16B per tile; this thread does chunks tid, tid+256
  const int r0 = tid >> 2;
  const int ke = (tid & 3) << 3;
  const u16* Ab = A + (size_t)(bm + r0) * K + ke;
  const u16* Wb = W + (size_t)(bn + r0) * K + ke;
  const size_t rstep = (size_t)64 * K;   // +64 rows

  auto issue = [&](int buf, int k0) {
    GLDS(Ab + k0, &As[buf][tid * 8]);
    GLDS(Ab + k0 + rstep, &As[buf][(tid + 256) * 8]);
    GLDS(Wb + k0, &Bs[buf][tid * 8]);
    GLDS(Wb + k0 + rstep, &Bs[buf][(tid + 256) * 8]);
  };

  issue(0, 0);
  int cur = 0;
  const int kq = (lane >> 4) << 3;
  const int mr = lane & 15;
  for (int k0 = 0; k0 < K; k0 += BK) {
    __syncthreads();                       // drains vmcnt: buf[cur] ready
    if (k0 + BK < K) issue(cur ^ 1, k0 + BK);  // overlaps with MFMA below
    bf16x8 af[4], bfr[4];
#pragma unroll
    for (int i = 0; i < 4; ++i)
      af[i] = *(const bf16x8*)(&As[cur][(wr + i * 16 + mr) * BK + kq]);
#pragma unroll
    for (int j = 0; j < 4; ++j)
      bfr[j] = *(const bf16x8*)(&Bs[cur][(wc + j * 16 + mr) * BK + kq]);
#pragma unroll
    for (int i = 0; i < 4; ++i)
#pragma unroll
      for (int j = 0; j < 4; ++j)
        acc[i][j] = __builtin_amdgcn_mfma_f32_16x16x32_bf16(af[i], bfr[j], acc[i][j], 0, 0, 0);
    cur ^= 1;
  }

  const int mlo = (lane >> 4) << 2;   // C/D: row=(lane>>4)*4+r, col=lane&15 (m89)
  const int nlo = lane & 15;
#pragma unroll
  for (int i = 0; i < 4; ++i) {
#pragma unroll
    for (int j = 0; j < 4; ++j) {
      int col = bn + wc + j * 16 + nlo;
      if (col < N) {
#pragma unroll
        for (int r = 0; r < 4; ++r) {
          int row = bm + wr + i * 16 + mlo + r;
          float v = acc[i][j][r];
          if constexpr (MODE == M_BF16) {
            C2[(size_t)row * N + col] = f2bf(v);
          } else if constexpr (MODE == M_PROJ) {
            C[(size_t)row * 96 + col] = v;
            if (col < 64) C2[((size_t)row << 6) + col] = f2bf(v);
          } else if constexpr (MODE == M_SOFTPLUS) {
            v += bias[col];
            C[(size_t)row * N + col] = (v > 20.0f) ? v : log1pf(__expf(v));
          } else if constexpr (MODE == M_GELU) {
            v += bias[col];
            float a = 0.7978845608028654f * (v + 0.044715f * v * v * v);
            float t = 1.0f - 2.0f / (__expf(2.0f * a) + 1.0f);
            C2[(size_t)row * N + col] = f2bf(0.5f * v * (1.0f + t));
          } else if constexpr (MODE == M_BIASRES) {
            C[(size_t)row * N + col] = v + bias[col] + resid[(size_t)row * N + col];
          }
        }
      }
    }
  }
}

// ---------------- LayerNorm helpers --------------------------------------
__device__ __forceinline__ void blockReduce2(float& s, float& q) {
#pragma unroll
  for (int o = 32; o > 0; o >>= 1) { s += __shfl_down(s, o, 64); q += __shfl_down(q, o, 64); }
  __shared__ float red[2][4];
  int lane = threadIdx.x & 63, wave = threadIdx.x >> 6;
  if (lane == 0) { red[0][wave] = s; red[1][wave] = q; }
  __syncthreads();
  s = red[0][0] + red[0][1] + red[0][2] + red[0][3];
  q = red[1][0] + red[1][1] + red[1][2] + red[1][3];
}

// out[b,l,:] = LN(x[b, path[l], :]) as bf16
__global__ __launch_bounds__(256) void ln_gather_k(
    const float* __restrict__ x, const int* __restrict__ path, u16* __restrict__ out)
{
  int b = blockIdx.x >> 12;
  int l = blockIdx.x & 4095;
  int src = path[l];
  const float* row = x + (((size_t)b * L_ + src) << 10);
  u16* orow = out + (((size_t)b * L_ + l) << 10);
  float v[4], s = 0.f, q = 0.f;
#pragma unroll
  for (int i = 0; i < 4; ++i) {
    v[i] = row[threadIdx.x + (i << 8)];
    s += v[i]; q += v[i] * v[i];
  }
  blockReduce2(s, q);
  float mean = s * (1.0f / 1024.0f);
  float var = q * (1.0f / 1024.0f) - mean * mean;
  float rstd = rsqrtf(var + 1e-6f);
#pragma unroll
  for (int i = 0; i < 4; ++i)
    orow[threadIdx.x + (i << 8)] = f2bf((v[i] - mean) * rstd);
}

// xnew = x + mo[b, prev[l], :] (mo bf16); lnout = LN(xnew) bf16
__global__ __launch_bounds__(256) void ln_scatter_k(
    const float* __restrict__ x, const int* __restrict__ prev,
    const u16* __restrict__ mo, float* __restrict__ xnew, u16* __restrict__ lnout)
{
  int b = blockIdx.x >> 12;
  int l = blockIdx.x & 4095;
  int pl = prev[l];
  const float* xr = x + (((size_t)b * L_ + l) << 10);
  const u16* mr_ = mo + (((size_t)b * L_ + pl) << 10);
  size_t base = ((size_t)blockIdx.x) << 10;
  float v[4], s = 0.f, q = 0.f;
#pragma unroll
  for (int i = 0; i < 4; ++i) {
    v[i] = xr[threadIdx.x + (i << 8)] + bf2f(mr_[threadIdx.x + (i << 8)]);
    s += v[i]; q += v[i] * v[i];
  }
  blockReduce2(s, q);
  float mean = s * (1.0f / 1024.0f);
  float var = q * (1.0f / 1024.0f) - mean * mean;
  float rstd = rsqrtf(var + 1e-6f);
#pragma unroll
  for (int i = 0; i < 4; ++i) {
    xnew[base + threadIdx.x + (i << 8)] = v[i];
    lnout[base + threadIdx.x + (i << 8)] = f2bf((v[i] - mean) * rstd);
  }
}

// ---------------- conv1d(4, causal) + SiLU; xz bf16 ----------------------
__global__ __launch_bounds__(256) void conv_silu_k(
    const u16* __restrict__ xz, const float* __restrict__ cw, const float* __restrict__ cb,
    u16* __restrict__ xc)
{
  int idx = blockIdx.x * 256 + threadIdx.x;  // B*L*Di
  int d = idx & 1023;
  int l = (idx >> 10) & 4095;
  int b = idx >> 22;
  float acc = cb[d];
#pragma unroll
  for (int k = 0; k < 4; ++k) {
    int ls = l + k - 3;
    if (ls >= 0)
      acc += cw[(d << 2) + k] * bf2f(xz[(((size_t)b * L_ + ls) << 11) + d]);
  }
  acc = acc * sigmoidf_(acc);
  xc[idx] = f2bf(acc);
}

// ---------------- selective scan, 3-phase chunked -------------------------
__global__ __launch_bounds__(256) void scan_p1_k(
    const float* __restrict__ dt, const u16* __restrict__ xc, const float* __restrict__ proj,
    const float* __restrict__ A_log, float* __restrict__ acum, float* __restrict__ hloc)
{
  int c = blockIdx.x & (NC_ - 1);
  int q = (blockIdx.x >> 6) & 3;
  int b = blockIdx.x >> 8;
  int d = (q << 8) + threadIdx.x;
  float Arow[N_];
#pragma unroll
  for (int n = 0; n < N_; ++n) Arow[n] = -__expf(A_log[(d << 4) + n]);
  float h[N_], ac[N_];
#pragma unroll
  for (int n = 0; n < N_; ++n) { h[n] = 0.0f; ac[n] = 1.0f; }
  int l0 = c << 6;
  for (int i = 0; i < LC_; ++i) {
    size_t rowb = (size_t)b * L_ + (l0 + i);
    float dtv = dt[(rowb << 10) + d];
    float xv = bf2f(xc[(rowb << 10) + d]);
    float dtx = dtv * xv;
    const float* Bp = proj + rowb * 96 + 64;
#pragma unroll
    for (int n = 0; n < N_; ++n) {
      float dA = __expf(dtv * Arow[n]);
      h[n] = dA * h[n] + dtx * Bp[n];
      ac[n] *= dA;
    }
  }
  size_t sb = ((((size_t)b << 10) + d) << 10) + (c << 4);
#pragma unroll
  for (int n = 0; n < N_; ++n) { acum[sb + n] = ac[n]; hloc[sb + n] = h[n]; }
}

__global__ __launch_bounds__(256) void scan_p2_k(
    const float* __restrict__ acum, const float* __restrict__ hloc, float* __restrict__ hin)
{
  int idx = blockIdx.x * 256 + threadIdx.x;  // B*1024*16
  int n = idx & 15;
  int dn = idx >> 4;
  size_t base = ((size_t)dn << 10) + n;
  float hs = 0.0f;
  for (int c = 0; c < NC_; ++c) {
    hin[base + (c << 4)] = hs;
    hs = acum[base + (c << 4)] * hs + hloc[base + (c << 4)];
  }
}

__global__ __launch_bounds__(256) void scan_p3_k(
    const float* __restrict__ dt, const u16* __restrict__ xc, const float* __restrict__ proj,
    const float* __restrict__ A_log, const float* __restrict__ Dp, const float* __restrict__ hin,
    const u16* __restrict__ xz, u16* __restrict__ yg)
{
  int c = blockIdx.x & (NC_ - 1);
  int q = (blockIdx.x >> 6) & 3;
  int b = blockIdx.x >> 8;
  int d = (q << 8) + threadIdx.x;
  float Arow[N_];
#pragma unroll
  for (int n = 0; n < N_; ++n) Arow[n] = -__expf(A_log[(d << 4) + n]);
  float h[N_];
  size_t sb = ((((size_t)b << 10) + d) << 10) + (c << 4);
#pragma unroll
  for (int n = 0; n < N_; ++n) h[n] = hin[sb + n];
  float Dv = Dp[d];
  int l0 = c << 6;
  for (int i = 0; i < LC_; ++i) {
    size_t rowb = (size_t)b * L_ + (l0 + i);
    float dtv = dt[(rowb << 10) + d];
    float xv = bf2f(xc[(rowb << 10) + d]);
    float dtx = dtv * xv;
    const float* Bp = proj + rowb * 96 + 64;
    const float* Cp = proj + rowb * 96 + 80;
    float y = 0.0f;
#pragma unroll
    for (int n = 0; n < N_; ++n) {
      float dA = __expf(dtv * Arow[n]);
      h[n] = dA * h[n] + dtx * Bp[n];
      y += h[n] * Cp[n];
    }
    y += Dv * xv;
    float zv = bf2f(xz[(rowb << 11) + 1024 + d]);
    yg[(rowb << 10) + d] = f2bf(y * zv * sigmoidf_(zv));
  }
}

// ---------------- driver ---------------------------------------------------
extern "C" void kernel_launch(void* const* d_in, const int* in_sizes, int n_in,
                              void* d_out, int out_size, void* d_ws, size_t ws_size,
                              hipStream_t stream)
{
  const float* x_in      = (const float*)d_in[0];
  const int*   path      = (const int*)d_in[1];
  const int*   path_rev  = (const int*)d_in[2];
  const float* in_proj_w = (const float*)d_in[3];
  const float* conv_w    = (const float*)d_in[4];
  const float* conv_b    = (const float*)d_in[5];
  const float* x_proj_w  = (const float*)d_in[6];
  const float* dt_proj_w = (const float*)d_in[7];
  const float* dt_proj_b = (const float*)d_in[8];
  const float* A_log     = (const float*)d_in[9];
  const float* Dp        = (const float*)d_in[10];
  const float* out_pw    = (const float*)d_in[11];
  const float* fc1_w     = (const float*)d_in[12];
  const float* fc1_b     = (const float*)d_in[13];
  const float* fc2_w     = (const float*)d_in[14];
  const float* fc2_b     = (const float*)d_in[15];
  float* out = (float*)d_out;

  char* w = (char*)d_ws;
  size_t off = 0;
  auto alloc = [&](size_t bytes) -> char* {
    char* p = w + off;
    off = (off + bytes + 255) & ~(size_t)255;
    return p;
  };
  u16*   wbf   = (u16*)  alloc((size_t)WBF_TOT * 2);     // bf16 weights (23 MB)
  u16*   ln_bf = (u16*)  alloc((size_t)BL_ * 1024 * 2);  // LN1 out; later LN2 out
  u16*   xz    = (u16*)  alloc((size_t)BL_ * 2048 * 2);  // bf16 xz; later mo (bf16)
  u16*   xc    = (u16*)  alloc((size_t)BL_ * 1024 * 2);
  char*  pool0 = alloc(0);
  float* proj  = (float*)alloc((size_t)BL_ * 96 * 4);
  u16*   dtr   = (u16*)  alloc((size_t)BL_ * 64 * 2);
  float* dt    = (float*)alloc((size_t)BL_ * 1024 * 4);
  float* acum  = (float*)alloc((size_t)2 * 1024 * NC_ * 16 * 4);
  float* hloc  = (float*)alloc((size_t)2 * 1024 * NC_ * 16 * 4);
  float* hin   = (float*)alloc((size_t)2 * 1024 * NC_ * 16 * 4);
  u16*   yg    = (u16*)  alloc((size_t)BL_ * 1024 * 2);
  float* xnew  = (float*)alloc((size_t)BL_ * 1024 * 4);
  u16*   mo    = xz;            // alias: z dead after scan_p3
  u16*   h1b   = (u16*)pool0;   // 64 MB over pool (proj..yg = 76 MB), dead by fc1

  const u16* w_inp = wbf;
  const u16* w_xp  = wbf + 2097152;
  const u16* w_dtp = wbf + 2228224;
  const u16* w_op  = wbf + 2293760;
  const u16* w_fc1 = wbf + 3342336;
  const u16* w_fc2 = wbf + 7536640;

  dim3 blk(256);
  cvt_w_k<<<WBF_TOT / 256, blk, 0, stream>>>(in_proj_w, x_proj_w, dt_proj_w, out_pw,
                                             fc1_w, fc2_w, wbf);
  ln_gather_k<<<BL_, blk, 0, stream>>>(x_in, path, ln_bf);
  gemm_bt<M_BF16><<<dim3(16, 64), blk, 0, stream>>>(ln_bf, w_inp, nullptr, xz, nullptr, nullptr, 8192, 2048, 1024);
  conv_silu_k<<<(BL_ * 1024) / 256, blk, 0, stream>>>(xz, conv_w, conv_b, xc);
  gemm_bt<M_PROJ><<<dim3(1, 64), blk, 0, stream>>>(xc, w_xp, proj, dtr, nullptr, nullptr, 8192, 96, 1024);
  gemm_bt<M_SOFTPLUS><<<dim3(8, 64), blk, 0, stream>>>(dtr, w_dtp, dt, nullptr, dt_proj_b, nullptr, 8192, 1024, 64);
  scan_p1_k<<<2 * 4 * NC_, blk, 0, stream>>>(dt, xc, proj, A_log, acum, hloc);
  scan_p2_k<<<(2 * 1024 * 16) / 256, blk, 0, stream>>>(acum, hloc, hin);
  scan_p3_k<<<2 * 4 * NC_, blk, 0, stream>>>(dt, xc, proj, A_log, Dp, hin, xz, yg);
  gemm_bt<M_BF16><<<dim3(8, 64), blk, 0, stream>>>(yg, w_op, nullptr, mo, nullptr, nullptr, 8192, 1024, 1024);
  ln_scatter_k<<<BL_, blk, 0, stream>>>(x_in, path_rev, mo, xnew, ln_bf);
  gemm_bt<M_GELU><<<dim3(32, 64), blk, 0, stream>>>(ln_bf, w_fc1, nullptr, h1b, fc1_b, nullptr, 8192, 4096, 1024);
  gemm_bt<M_BIASRES><<<dim3(8, 64), blk, 0, stream>>>(h1b, w_fc2, out, nullptr, fc2_b, xnew, 8192, 1024, 4096);
}

// Round 6
// 632.963 us; speedup vs baseline: 2.5683x; 1.0082x over previous
//
#include <hip/hip_runtime.h>
#include <cstdint>
#include <cstddef>

typedef unsigned short u16;
typedef __bf16 bf16x8 __attribute__((ext_vector_type(8)));
typedef float f32x4 __attribute__((ext_vector_type(4)));

#define B_ 2
#define L_ 4096
#define D_ 1024
#define N_ 16
#define BL_ 8192
#define NC_ 64   /* scan chunks */
#define LC_ 64   /* steps per chunk */

__device__ __forceinline__ float bf2f(u16 h) {
  union { unsigned int u; float f; } v; v.u = ((unsigned int)h) << 16; return v.f;
}
__device__ __forceinline__ u16 f2bf(float f) {
  union { float f; unsigned int u; } v; v.f = f;
  unsigned int r = v.u + 0x7FFFu + ((v.u >> 16) & 1u);
  return (u16)(r >> 16);
}
__device__ __forceinline__ float sigmoidf_(float x) { return 1.0f / (1.0f + __expf(-x)); }

// ---- weight fp32->bf16 pre-conversion (x_proj padded to 128 rows) --------
#define WBF_TOT 11730944
__global__ __launch_bounds__(256) void cvt_w_k(
    const float* __restrict__ s0, const float* __restrict__ s1,
    const float* __restrict__ s2, const float* __restrict__ s3,
    const float* __restrict__ s4, const float* __restrict__ s5,
    u16* __restrict__ dst)
{
  int i = blockIdx.x * 256 + threadIdx.x;
  if (i >= WBF_TOT) return;
  float v;
  if (i < 2097152) v = s0[i];
  else if (i < 2228224) { int j = i - 2097152; v = (j < 98304) ? s1[j] : 0.0f; }
  else if (i < 2293760) v = s2[i - 2228224];
  else if (i < 3342336) v = s3[i - 2293760];
  else if (i < 7536640) v = s4[i - 3342336];
  else v = s5[i - 7536640];
  dst[i] = f2bf(v);
}

// ---------------- GEMM: C = A[M,K] @ W[N,K]^T, both bf16 -------------------
// 3-stage LDS ring. Pattern per iter: s_waitcnt vmcnt(4) [my loads for buf
// cur done] -> s_barrier [ALL waves' loads done] -> issue batch k+2 -> MFMA.
// vmcnt never drains to 0 mid-loop; each batch gets ~2 MFMA phases to land.
// XCD-aware swizzle (id%8 = XCD owns an M-band).
#define BM 128
#define BN 128
#define BK 32

enum { M_BF16 = 0, M_PROJ = 1, M_SOFTPLUS = 2, M_GELU = 3, M_BIASRES = 4 };

#define GLDS(gp, lp) __builtin_amdgcn_global_load_lds( \
    (const __attribute__((address_space(1))) void*)(gp), \
    (__attribute__((address_space(3))) void*)(lp), 16, 0, 0)

template<int MODE>
__global__ __launch_bounds__(256) void gemm_bt(
    const u16* __restrict__ A, const u16* __restrict__ W,
    float* __restrict__ C, u16* __restrict__ C2,
    const float* __restrict__ bias, const u16* __restrict__ resid,
    int M, int N, int K)
{
  __shared__ __align__(16) u16 As[3][BM * BK];
  __shared__ __align__(16) u16 Bs[3][BN * BK];

  // XCD swizzle: grid y is always a multiple of 8 here.
  const int id = blockIdx.x + gridDim.x * blockIdx.y;
  const int xcd = id & 7;
  const int q = id >> 3;
  const int bandH = gridDim.y >> 3;
  const int xs = q % gridDim.x;
  const int ys = xcd * bandH + q / gridDim.x;
  const int bm = ys * BM;
  const int bn = xs * BN;

  const int tid = threadIdx.x;
  const int lane = tid & 63;
  const int wave = tid >> 6;
  const int wr = (wave >> 1) * 64;
  const int wc = (wave & 1) * 64;

  f32x4 acc[4][4];
#pragma unroll
  for (int i = 0; i < 4; ++i)
#pragma unroll
    for (int j = 0; j < 4; ++j)
#pragma unroll
      for (int r = 0; r < 4; ++r) acc[i][j][r] = 0.0f;

  // staging: 512 chunks of 16B per tile; this thread does chunks tid, tid+256
  const int r0 = tid >> 2;
  const int ke = (tid & 3) << 3;
  const u16* Ab = A + (size_t)(bm + r0) * K + ke;
  const u16* Wb = W + (size_t)(bn + r0) * K + ke;
  const size_t rstep = (size_t)64 * K;   // +64 rows

  auto issue = [&](int buf, int k0) {
    GLDS(Ab + k0, &As[buf][tid * 8]);
    GLDS(Ab + k0 + rstep, &As[buf][(tid + 256) * 8]);
    GLDS(Wb + k0, &Bs[buf][tid * 8]);
    GLDS(Wb + k0 + rstep, &Bs[buf][(tid + 256) * 8]);
  };

  issue(0, 0);
  if (BK < K) issue(1, BK);
  int cur = 0;
  const int kq = (lane >> 4) << 3;
  const int mr = lane & 15;
  for (int k0 = 0; k0 < K; k0 += BK) {
    // 1) certify MY loads for buffer cur (oldest batch) have landed:
    if (k0 + BK < K) asm volatile("s_waitcnt vmcnt(4)" ::: "memory");
    else             asm volatile("s_waitcnt vmcnt(0)" ::: "memory");
    // 2) certify ALL waves' loads for buffer cur have landed; also proves
    //    every wave finished reading buffer (cur+2)%3 (their iter-(k-1) LDS
    //    reads complete before their MFMAs, which precede this barrier).
    asm volatile("s_barrier" ::: "memory");
    // 3) refill the buffer freed at iter k-1 (no reader until iter k+2):
    int nb = cur + 2; if (nb >= 3) nb -= 3;
    if (k0 + 2 * BK < K) issue(nb, k0 + 2 * BK);
    bf16x8 af[4], bfr[4];
#pragma unroll
    for (int i = 0; i < 4; ++i)
      af[i] = *(const bf16x8*)(&As[cur][(wr + i * 16 + mr) * BK + kq]);
#pragma unroll
    for (int j = 0; j < 4; ++j)
      bfr[j] = *(const bf16x8*)(&Bs[cur][(wc + j * 16 + mr) * BK + kq]);
#pragma unroll
    for (int i = 0; i < 4; ++i)
#pragma unroll
      for (int j = 0; j < 4; ++j)
        acc[i][j] = __builtin_amdgcn_mfma_f32_16x16x32_bf16(af[i], bfr[j], acc[i][j], 0, 0, 0);
    ++cur; if (cur == 3) cur = 0;
  }

  const int mlo = (lane >> 4) << 2;   // C/D: row=(lane>>4)*4+r, col=lane&15 (m89)
  const int nlo = lane & 15;
#pragma unroll
  for (int i = 0; i < 4; ++i) {
#pragma unroll
    for (int j = 0; j < 4; ++j) {
      int col = bn + wc + j * 16 + nlo;
      if (col < N) {
#pragma unroll
        for (int r = 0; r < 4; ++r) {
          int row = bm + wr + i * 16 + mlo + r;
          float v = acc[i][j][r];
          if constexpr (MODE == M_BF16) {
            C2[(size_t)row * N + col] = f2bf(v);
          } else if constexpr (MODE == M_PROJ) {
            C[(size_t)row * 96 + col] = v;
            if (col < 64) C2[((size_t)row << 6) + col] = f2bf(v);
          } else if constexpr (MODE == M_SOFTPLUS) {
            v += bias[col];
            v = (v > 20.0f) ? v : log1pf(__expf(v));
            C2[(size_t)row * N + col] = f2bf(v);
          } else if constexpr (MODE == M_GELU) {
            v += bias[col];
            float a = 0.7978845608028654f * (v + 0.044715f * v * v * v);
            float t = 1.0f - 2.0f / (__expf(2.0f * a) + 1.0f);
            C2[(size_t)row * N + col] = f2bf(0.5f * v * (1.0f + t));
          } else if constexpr (MODE == M_BIASRES) {
            C[(size_t)row * N + col] = v + bias[col] + bf2f(resid[(size_t)row * N + col]);
          }
        }
      }
    }
  }
}

// ---------------- LayerNorm helpers --------------------------------------
__device__ __forceinline__ void blockReduce2(float& s, float& q) {
#pragma unroll
  for (int o = 32; o > 0; o >>= 1) { s += __shfl_down(s, o, 64); q += __shfl_down(q, o, 64); }
  __shared__ float red[2][4];
  int lane = threadIdx.x & 63, wave = threadIdx.x >> 6;
  if (lane == 0) { red[0][wave] = s; red[1][wave] = q; }
  __syncthreads();
  s = red[0][0] + red[0][1] + red[0][2] + red[0][3];
  q = red[1][0] + red[1][1] + red[1][2] + red[1][3];
}

// out[b,l,:] = LN(x[b, path[l], :]) as bf16
__global__ __launch_bounds__(256) void ln_gather_k(
    const float* __restrict__ x, const int* __restrict__ path, u16* __restrict__ out)
{
  int b = blockIdx.x >> 12;
  int l = blockIdx.x & 4095;
  int src = path[l];
  const float* row = x + (((size_t)b * L_ + src) << 10);
  u16* orow = out + (((size_t)b * L_ + l) << 10);
  float v[4], s = 0.f, q = 0.f;
#pragma unroll
  for (int i = 0; i < 4; ++i) {
    v[i] = row[threadIdx.x + (i << 8)];
    s += v[i]; q += v[i] * v[i];
  }
  blockReduce2(s, q);
  float mean = s * (1.0f / 1024.0f);
  float var = q * (1.0f / 1024.0f) - mean * mean;
  float rstd = rsqrtf(var + 1e-6f);
#pragma unroll
  for (int i = 0; i < 4; ++i)
    orow[threadIdx.x + (i << 8)] = f2bf((v[i] - mean) * rstd);
}

// xnew = x + mo[b, prev[l], :] (mo bf16); xnew stored bf16; lnout = LN(xnew)
__global__ __launch_bounds__(256) void ln_scatter_k(
    const float* __restrict__ x, const int* __restrict__ prev,
    const u16* __restrict__ mo, u16* __restrict__ xnew, u16* __restrict__ lnout)
{
  int b = blockIdx.x >> 12;
  int l = blockIdx.x & 4095;
  int pl = prev[l];
  const float* xr = x + (((size_t)b * L_ + l) << 10);
  const u16* mr_ = mo + (((size_t)b * L_ + pl) << 10);
  size_t base = ((size_t)blockIdx.x) << 10;
  float v[4], s = 0.f, q = 0.f;
#pragma unroll
  for (int i = 0; i < 4; ++i) {
    v[i] = xr[threadIdx.x + (i << 8)] + bf2f(mr_[threadIdx.x + (i << 8)]);
    s += v[i]; q += v[i] * v[i];
  }
  blockReduce2(s, q);
  float mean = s * (1.0f / 1024.0f);
  float var = q * (1.0f / 1024.0f) - mean * mean;
  float rstd = rsqrtf(var + 1e-6f);
#pragma unroll
  for (int i = 0; i < 4; ++i) {
    xnew[base + threadIdx.x + (i << 8)] = f2bf(v[i]);
    lnout[base + threadIdx.x + (i << 8)] = f2bf((v[i] - mean) * rstd);
  }
}

// ---------------- conv1d(4, causal) + SiLU; xz bf16 ----------------------
__global__ __launch_bounds__(256) void conv_silu_k(
    const u16* __restrict__ xz, const float* __restrict__ cw, const float* __restrict__ cb,
    u16* __restrict__ xc)
{
  int idx = blockIdx.x * 256 + threadIdx.x;  // B*L*Di
  int d = idx & 1023;
  int l = (idx >> 10) & 4095;
  int b = idx >> 22;
  float acc = cb[d];
#pragma unroll
  for (int k = 0; k < 4; ++k) {
    int ls = l + k - 3;
    if (ls >= 0)
      acc += cw[(d << 2) + k] * bf2f(xz[(((size_t)b * L_ + ls) << 11) + d]);
  }
  acc = acc * sigmoidf_(acc);
  xc[idx] = f2bf(acc);
}

// ---------------- selective scan, 3-phase chunked -------------------------
__global__ __launch_bounds__(256) void scan_p1_k(
    const u16* __restrict__ dt, const u16* __restrict__ xc, const float* __restrict__ proj,
    const float* __restrict__ A_log, float* __restrict__ acum, float* __restrict__ hloc)
{
  int c = blockIdx.x & (NC_ - 1);
  int q = (blockIdx.x >> 6) & 3;
  int b = blockIdx.x >> 8;
  int d = (q << 8) + threadIdx.x;
  float Arow[N_];
#pragma unroll
  for (int n = 0; n < N_; ++n) Arow[n] = -__expf(A_log[(d << 4) + n]);
  float h[N_], ac[N_];
#pragma unroll
  for (int n = 0; n < N_; ++n) { h[n] = 0.0f; ac[n] = 1.0f; }
  int l0 = c << 6;
  for (int i = 0; i < LC_; ++i) {
    size_t rowb = (size_t)b * L_ + (l0 + i);
    float dtv = bf2f(dt[(rowb << 10) + d]);
    float xv = bf2f(xc[(rowb << 10) + d]);
    float dtx = dtv * xv;
    const float* Bp = proj + rowb * 96 + 64;
#pragma unroll
    for (int n = 0; n < N_; ++n) {
      float dA = __expf(dtv * Arow[n]);
      h[n] = dA * h[n] + dtx * Bp[n];
      ac[n] *= dA;
    }
  }
  size_t sb = ((((size_t)b << 10) + d) << 10) + (c << 4);
#pragma unroll
  for (int n = 0; n < N_; ++n) { acum[sb + n] = ac[n]; hloc[sb + n] = h[n]; }
}

__global__ __launch_bounds__(256) void scan_p2_k(
    const float* __restrict__ acum, const float* __restrict__ hloc, float* __restrict__ hin)
{
  int idx = blockIdx.x * 256 + threadIdx.x;  // B*1024*16
  int n = idx & 15;
  int dn = idx >> 4;
  size_t base = ((size_t)dn << 10) + n;
  float hs = 0.0f;
  for (int c = 0; c < NC_; ++c) {
    hin[base + (c << 4)] = hs;
    hs = acum[base + (c << 4)] * hs + hloc[base + (c << 4)];
  }
}

__global__ __launch_bounds__(256) void scan_p3_k(
    const u16* __restrict__ dt, const u16* __restrict__ xc, const float* __restrict__ proj,
    const float* __restrict__ A_log, const float* __restrict__ Dp, const float* __restrict__ hin,
    const u16* __restrict__ xz, u16* __restrict__ yg)
{
  int c = blockIdx.x & (NC_ - 1);
  int q = (blockIdx.x >> 6) & 3;
  int b = blockIdx.x >> 8;
  int d = (q << 8) + threadIdx.x;
  float Arow[N_];
#pragma unroll
  for (int n = 0; n < N_; ++n) Arow[n] = -__expf(A_log[(d << 4) + n]);
  float h[N_];
  size_t sb = ((((size_t)b << 10) + d) << 10) + (c << 4);
#pragma unroll
  for (int n = 0; n < N_; ++n) h[n] = hin[sb + n];
  float Dv = Dp[d];
  int l0 = c << 6;
  for (int i = 0; i < LC_; ++i) {
    size_t rowb = (size_t)b * L_ + (l0 + i);
    float dtv = bf2f(dt[(rowb << 10) + d]);
    float xv = bf2f(xc[(rowb << 10) + d]);
    float dtx = dtv * xv;
    const float* Bp = proj + rowb * 96 + 64;
    const float* Cp = proj + rowb * 96 + 80;
    float y = 0.0f;
#pragma unroll
    for (int n = 0; n < N_; ++n) {
      float dA = __expf(dtv * Arow[n]);
      h[n] = dA * h[n] + dtx * Bp[n];
      y += h[n] * Cp[n];
    }
    y += Dv * xv;
    float zv = bf2f(xz[(rowb << 11) + 1024 + d]);
    yg[(rowb << 10) + d] = f2bf(y * zv * sigmoidf_(zv));
  }
}

// ---------------- driver ---------------------------------------------------
extern "C" void kernel_launch(void* const* d_in, const int* in_sizes, int n_in,
                              void* d_out, int out_size, void* d_ws, size_t ws_size,
                              hipStream_t stream)
{
  const float* x_in      = (const float*)d_in[0];
  const int*   path      = (const int*)d_in[1];
  const int*   path_rev  = (const int*)d_in[2];
  const float* in_proj_w = (const float*)d_in[3];
  const float* conv_w    = (const float*)d_in[4];
  const float* conv_b    = (const float*)d_in[5];
  const float* x_proj_w  = (const float*)d_in[6];
  const float* dt_proj_w = (const float*)d_in[7];
  const float* dt_proj_b = (const float*)d_in[8];
  const float* A_log     = (const float*)d_in[9];
  const float* Dp        = (const float*)d_in[10];
  const float* out_pw    = (const float*)d_in[11];
  const float* fc1_w     = (const float*)d_in[12];
  const float* fc1_b     = (const float*)d_in[13];
  const float* fc2_w     = (const float*)d_in[14];
  const float* fc2_b     = (const float*)d_in[15];
  float* out = (float*)d_out;

  char* w = (char*)d_ws;
  size_t off = 0;
  auto alloc = [&](size_t bytes) -> char* {
    char* p = w + off;
    off = (off + bytes + 255) & ~(size_t)255;
    return p;
  };
  u16*   wbf   = (u16*)  alloc((size_t)WBF_TOT * 2);     // bf16 weights (23 MB)
  u16*   ln_bf = (u16*)  alloc((size_t)BL_ * 1024 * 2);  // LN1 out; later LN2 out
  u16*   xz    = (u16*)  alloc((size_t)BL_ * 2048 * 2);  // bf16 xz; later mo (bf16)
  u16*   xc    = (u16*)  alloc((size_t)BL_ * 1024 * 2);
  char*  pool0 = alloc(0);
  float* proj  = (float*)alloc((size_t)BL_ * 96 * 4);    // 3 MB
  u16*   dtr   = (u16*)  alloc((size_t)BL_ * 64 * 2);    // 1 MB
  u16*   dt    = (u16*)  alloc((size_t)BL_ * 1024 * 2);  // 16 MB
  float* acum  = (float*)alloc((size_t)2 * 1024 * NC_ * 16 * 4);  // 8 MB
  float* hloc  = (float*)alloc((size_t)2 * 1024 * NC_ * 16 * 4);  // 8 MB
  float* hin   = (float*)alloc((size_t)2 * 1024 * NC_ * 16 * 4);  // 8 MB
  u16*   yg    = (u16*)  alloc((size_t)BL_ * 1024 * 2);  // 16 MB  (pool total 60 MB)
  u16*   h1b   = (u16*)pool0;   // 64 MB, aliases dead pool (proj..yg) by fc1 time
  // xnew OUTSIDE h1b's 64 MB footprint:
  off = (size_t)(pool0 - w) + ((size_t)BL_ * 4096 * 2);
  u16*   xnew  = (u16*)  alloc((size_t)BL_ * 1024 * 2);  // 16 MB, bf16 residual
  u16*   mo    = xz;            // alias: z dead after scan_p3

  const u16* w_inp = wbf;
  const u16* w_xp  = wbf + 2097152;
  const u16* w_dtp = wbf + 2228224;
  const u16* w_op  = wbf + 2293760;
  const u16* w_fc1 = wbf + 3342336;
  const u16* w_fc2 = wbf + 7536640;

  dim3 blk(256);
  cvt_w_k<<<WBF_TOT / 256, blk, 0, stream>>>(in_proj_w, x_proj_w, dt_proj_w, out_pw,
                                             fc1_w, fc2_w, wbf);
  ln_gather_k<<<BL_, blk, 0, stream>>>(x_in, path, ln_bf);
  gemm_bt<M_BF16><<<dim3(16, 64), blk, 0, stream>>>(ln_bf, w_inp, nullptr, xz, nullptr, nullptr, 8192, 2048, 1024);
  conv_silu_k<<<(BL_ * 1024) / 256, blk, 0, stream>>>(xz, conv_w, conv_b, xc);
  gemm_bt<M_PROJ><<<dim3(1, 64), blk, 0, stream>>>(xc, w_xp, proj, dtr, nullptr, nullptr, 8192, 96, 1024);
  gemm_bt<M_SOFTPLUS><<<dim3(8, 64), blk, 0, stream>>>(dtr, w_dtp, nullptr, dt, dt_proj_b, nullptr, 8192, 1024, 64);
  scan_p1_k<<<2 * 4 * NC_, blk, 0, stream>>>(dt, xc, proj, A_log, acum, hloc);
  scan_p2_k<<<(2 * 1024 * 16) / 256, blk, 0, stream>>>(acum, hloc, hin);
  scan_p3_k<<<2 * 4 * NC_, blk, 0, stream>>>(dt, xc, proj, A_log, Dp, hin, xz, yg);
  gemm_bt<M_BF16><<<dim3(8, 64), blk, 0, stream>>>(yg, w_op, nullptr, mo, nullptr, nullptr, 8192, 1024, 1024);
  ln_scatter_k<<<BL_, blk, 0, stream>>>(x_in, path_rev, mo, xnew, ln_bf);
  gemm_bt<M_GELU><<<dim3(32, 64), blk, 0, stream>>>(ln_bf, w_fc1, nullptr, h1b, fc1_b, nullptr, 8192, 4096, 1024);
  gemm_bt<M_BIASRES><<<dim3(8, 64), blk, 0, stream>>>(h1b, w_fc2, out, nullptr, fc2_b, xnew, 8192, 1024, 4096);
}

// Round 7
// 624.183 us; speedup vs baseline: 2.6044x; 1.0141x over previous
//
#include <hip/hip_runtime.h>
#include <cstdint>
#include <cstddef>

typedef unsigned short u16;
typedef __bf16 bf16x8 __attribute__((ext_vector_type(8)));
typedef float f32x4 __attribute__((ext_vector_type(4)));

#define B_ 2
#define L_ 4096
#define D_ 1024
#define N_ 16
#define BL_ 8192
#define NC_ 64   /* scan chunks */
#define LC_ 64   /* steps per chunk */

__device__ __forceinline__ float bf2f(u16 h) {
  union { unsigned int u; float f; } v; v.u = ((unsigned int)h) << 16; return v.f;
}
__device__ __forceinline__ u16 f2bf(float f) {
  union { float f; unsigned int u; } v; v.f = f;
  unsigned int r = v.u + 0x7FFFu + ((v.u >> 16) & 1u);
  return (u16)(r >> 16);
}
__device__ __forceinline__ float sigmoidf_(float x) { return 1.0f / (1.0f + __expf(-x)); }

// ---- weight fp32->bf16 pre-conversion (x_proj padded to 128 rows) --------
#define WBF_TOT 11730944
__global__ __launch_bounds__(256) void cvt_w_k(
    const float* __restrict__ s0, const float* __restrict__ s1,
    const float* __restrict__ s2, const float* __restrict__ s3,
    const float* __restrict__ s4, const float* __restrict__ s5,
    u16* __restrict__ dst)
{
  int i = blockIdx.x * 256 + threadIdx.x;
  if (i >= WBF_TOT) return;
  float v;
  if (i < 2097152) v = s0[i];
  else if (i < 2228224) { int j = i - 2097152; v = (j < 98304) ? s1[j] : 0.0f; }
  else if (i < 2293760) v = s2[i - 2228224];
  else if (i < 3342336) v = s3[i - 2293760];
  else if (i < 7536640) v = s4[i - 3342336];
  else v = s5[i - 7536640];
  dst[i] = f2bf(v);
}

// ---------------- GEMM: C = A[M,K] @ W[N,K]^T, both bf16 -------------------
// 3-stage LDS ring (wait vmcnt(4) -> s_barrier -> issue k+2 -> MFMA).
// XOR bank swizzle: k-chunk q of row r lives at LDS slot q^(r&3), applied on
// the GLOBAL address side so global_load_lds writes stay linear. Frag reads
// land on 8 distinct bank-starts x 4 lanes (uniform minimum) vs the naive
// layout's 4 starts x 8 lanes (2x rounds; measured +4 cyc/ds_read_b128).
// K templated: full unroll (<=32 iters) folds ring indices/addresses.
#define BM 128
#define BN 128
#define BK 32

enum { M_BF16 = 0, M_PROJ = 1, M_SOFTPLUS = 2, M_GELU = 3, M_BIASRES = 4 };

#define GLDS(gp, lp) __builtin_amdgcn_global_load_lds( \
    (const __attribute__((address_space(1))) void*)(gp), \
    (__attribute__((address_space(3))) void*)(lp), 16, 0, 0)

template<int MODE, int K>
__global__ __launch_bounds__(256) void gemm_bt(
    const u16* __restrict__ A, const u16* __restrict__ W,
    float* __restrict__ C, u16* __restrict__ C2,
    const float* __restrict__ bias, const u16* __restrict__ resid,
    int M, int N)
{
  __shared__ __align__(16) u16 As[3][BM * BK];
  __shared__ __align__(16) u16 Bs[3][BN * BK];

  // XCD swizzle: grid y is always a multiple of 8 here.
  const int id = blockIdx.x + gridDim.x * blockIdx.y;
  const int xcd = id & 7;
  const int qq = id >> 3;
  const int bandH = gridDim.y >> 3;
  const int xs = qq % gridDim.x;
  const int ys = xcd * bandH + qq / gridDim.x;
  const int bm = ys * BM;
  const int bn = xs * BN;

  const int tid = threadIdx.x;
  const int lane = tid & 63;
  const int wave = tid >> 6;
  const int wr = (wave >> 1) * 64;
  const int wc = (wave & 1) * 64;

  f32x4 acc[4][4];
#pragma unroll
  for (int i = 0; i < 4; ++i)
#pragma unroll
    for (int j = 0; j < 4; ++j)
#pragma unroll
      for (int r = 0; r < 4; ++r) acc[i][j][r] = 0.0f;

  // staging: thread handles chunks tid and tid+256 (rows r0, r0+64), LDS
  // dest linear (chunk*16B). XOR swizzle on the global k-chunk: position
  // tid&3 receives global chunk (tid&3)^(r0&3). (r0+64)&3 == r0&3.
  const int r0 = tid >> 2;
  const int ke = (((tid & 3) ^ (r0 & 3)) << 3);
  const u16* Ab = A + (size_t)(bm + r0) * K + ke;
  const u16* Wb = W + (size_t)(bn + r0) * K + ke;
  constexpr size_t rstep = (size_t)64 * K;   // +64 rows

  auto issue = [&](int buf, int k0) {
    GLDS(Ab + k0, &As[buf][tid * 8]);
    GLDS(Ab + k0 + rstep, &As[buf][(tid + 256) * 8]);
    GLDS(Wb + k0, &Bs[buf][tid * 8]);
    GLDS(Wb + k0 + rstep, &Bs[buf][(tid + 256) * 8]);
  };

  issue(0, 0);
  if constexpr (BK < K) issue(1, BK);

  const int mr = lane & 15;
  // frag read: row R = wr|wc + i*16 + mr (R&3 == mr&3), k-chunk q = lane>>4
  // stored at slot q^(R&3):
  const int pos = (((lane >> 4) ^ (mr & 3)) << 3);
  constexpr int NIT = K / BK;

  auto step = [&](int it) {
    // 1) my loads for buffer (it%3) have landed (2 newer batches in flight):
    if (it + 1 < NIT) asm volatile("s_waitcnt vmcnt(4)" ::: "memory");
    else              asm volatile("s_waitcnt vmcnt(0)" ::: "memory");
    // 2) all waves' loads landed; buffer (it+2)%3 free (read at it-1):
    asm volatile("s_barrier" ::: "memory");
    // 3) refill freed buffer:
    if (it + 2 < NIT) issue((it + 2) % 3, (it + 2) * BK);
    const int cur = it % 3;
    bf16x8 af[4], bfr[4];
#pragma unroll
    for (int i = 0; i < 4; ++i)
      af[i] = *(const bf16x8*)(&As[cur][(wr + i * 16 + mr) * BK + pos]);
#pragma unroll
    for (int j = 0; j < 4; ++j)
      bfr[j] = *(const bf16x8*)(&Bs[cur][(wc + j * 16 + mr) * BK + pos]);
#pragma unroll
    for (int i = 0; i < 4; ++i)
#pragma unroll
      for (int j = 0; j < 4; ++j)
        acc[i][j] = __builtin_amdgcn_mfma_f32_16x16x32_bf16(af[i], bfr[j], acc[i][j], 0, 0, 0);
  };

  if constexpr (NIT <= 32) {
#pragma unroll
    for (int it = 0; it < NIT; ++it) step(it);
  } else {
#pragma unroll 6
    for (int it = 0; it < NIT; ++it) step(it);
  }

  const int mlo = (lane >> 4) << 2;   // C/D: row=(lane>>4)*4+r, col=lane&15 (m89)
  const int nlo = lane & 15;
#pragma unroll
  for (int i = 0; i < 4; ++i) {
#pragma unroll
    for (int j = 0; j < 4; ++j) {
      int col = bn + wc + j * 16 + nlo;
      if (col < N) {
#pragma unroll
        for (int r = 0; r < 4; ++r) {
          int row = bm + wr + i * 16 + mlo + r;
          float v = acc[i][j][r];
          if constexpr (MODE == M_BF16) {
            C2[(size_t)row * N + col] = f2bf(v);
          } else if constexpr (MODE == M_PROJ) {
            C[(size_t)row * 96 + col] = v;
            if (col < 64) C2[((size_t)row << 6) + col] = f2bf(v);
          } else if constexpr (MODE == M_SOFTPLUS) {
            v += bias[col];
            v = (v > 20.0f) ? v : log1pf(__expf(v));
            C2[(size_t)row * N + col] = f2bf(v);
          } else if constexpr (MODE == M_GELU) {
            v += bias[col];
            float a = 0.7978845608028654f * (v + 0.044715f * v * v * v);
            float t = 1.0f - 2.0f / (__expf(2.0f * a) + 1.0f);
            C2[(size_t)row * N + col] = f2bf(0.5f * v * (1.0f + t));
          } else if constexpr (MODE == M_BIASRES) {
            C[(size_t)row * N + col] = v + bias[col] + bf2f(resid[(size_t)row * N + col]);
          }
        }
      }
    }
  }
}

// ---------------- LayerNorm helpers --------------------------------------
__device__ __forceinline__ void blockReduce2(float& s, float& q) {
#pragma unroll
  for (int o = 32; o > 0; o >>= 1) { s += __shfl_down(s, o, 64); q += __shfl_down(q, o, 64); }
  __shared__ float red[2][4];
  int lane = threadIdx.x & 63, wave = threadIdx.x >> 6;
  if (lane == 0) { red[0][wave] = s; red[1][wave] = q; }
  __syncthreads();
  s = red[0][0] + red[0][1] + red[0][2] + red[0][3];
  q = red[1][0] + red[1][1] + red[1][2] + red[1][3];
}

// out[b,l,:] = LN(x[b, path[l], :]) as bf16
__global__ __launch_bounds__(256) void ln_gather_k(
    const float* __restrict__ x, const int* __restrict__ path, u16* __restrict__ out)
{
  int b = blockIdx.x >> 12;
  int l = blockIdx.x & 4095;
  int src = path[l];
  const float* row = x + (((size_t)b * L_ + src) << 10);
  u16* orow = out + (((size_t)b * L_ + l) << 10);
  float v[4], s = 0.f, q = 0.f;
#pragma unroll
  for (int i = 0; i < 4; ++i) {
    v[i] = row[threadIdx.x + (i << 8)];
    s += v[i]; q += v[i] * v[i];
  }
  blockReduce2(s, q);
  float mean = s * (1.0f / 1024.0f);
  float var = q * (1.0f / 1024.0f) - mean * mean;
  float rstd = rsqrtf(var + 1e-6f);
#pragma unroll
  for (int i = 0; i < 4; ++i)
    orow[threadIdx.x + (i << 8)] = f2bf((v[i] - mean) * rstd);
}

// xnew = x + mo[b, prev[l], :] (mo bf16); xnew stored bf16; lnout = LN(xnew)
__global__ __launch_bounds__(256) void ln_scatter_k(
    const float* __restrict__ x, const int* __restrict__ prev,
    const u16* __restrict__ mo, u16* __restrict__ xnew, u16* __restrict__ lnout)
{
  int b = blockIdx.x >> 12;
  int l = blockIdx.x & 4095;
  int pl = prev[l];
  const float* xr = x + (((size_t)b * L_ + l) << 10);
  const u16* mr_ = mo + (((size_t)b * L_ + pl) << 10);
  size_t base = ((size_t)blockIdx.x) << 10;
  float v[4], s = 0.f, q = 0.f;
#pragma unroll
  for (int i = 0; i < 4; ++i) {
    v[i] = xr[threadIdx.x + (i << 8)] + bf2f(mr_[threadIdx.x + (i << 8)]);
    s += v[i]; q += v[i] * v[i];
  }
  blockReduce2(s, q);
  float mean = s * (1.0f / 1024.0f);
  float var = q * (1.0f / 1024.0f) - mean * mean;
  float rstd = rsqrtf(var + 1e-6f);
#pragma unroll
  for (int i = 0; i < 4; ++i) {
    xnew[base + threadIdx.x + (i << 8)] = f2bf(v[i]);
    lnout[base + threadIdx.x + (i << 8)] = f2bf((v[i] - mean) * rstd);
  }
}

// ---------------- conv1d(4, causal) + SiLU; xz bf16 ----------------------
__global__ __launch_bounds__(256) void conv_silu_k(
    const u16* __restrict__ xz, const float* __restrict__ cw, const float* __restrict__ cb,
    u16* __restrict__ xc)
{
  int idx = blockIdx.x * 256 + threadIdx.x;  // B*L*Di
  int d = idx & 1023;
  int l = (idx >> 10) & 4095;
  int b = idx >> 22;
  float acc = cb[d];
#pragma unroll
  for (int k = 0; k < 4; ++k) {
    int ls = l + k - 3;
    if (ls >= 0)
      acc += cw[(d << 2) + k] * bf2f(xz[(((size_t)b * L_ + ls) << 11) + d]);
  }
  acc = acc * sigmoidf_(acc);
  xc[idx] = f2bf(acc);
}

// ---------------- selective scan, 3-phase chunked -------------------------
__global__ __launch_bounds__(256) void scan_p1_k(
    const u16* __restrict__ dt, const u16* __restrict__ xc, const float* __restrict__ proj,
    const float* __restrict__ A_log, float* __restrict__ acum, float* __restrict__ hloc)
{
  int c = blockIdx.x & (NC_ - 1);
  int q = (blockIdx.x >> 6) & 3;
  int b = blockIdx.x >> 8;
  int d = (q << 8) + threadIdx.x;
  float Arow[N_];
#pragma unroll
  for (int n = 0; n < N_; ++n) Arow[n] = -__expf(A_log[(d << 4) + n]);
  float h[N_], ac[N_];
#pragma unroll
  for (int n = 0; n < N_; ++n) { h[n] = 0.0f; ac[n] = 1.0f; }
  int l0 = c << 6;
  for (int i = 0; i < LC_; ++i) {
    size_t rowb = (size_t)b * L_ + (l0 + i);
    float dtv = bf2f(dt[(rowb << 10) + d]);
    float xv = bf2f(xc[(rowb << 10) + d]);
    float dtx = dtv * xv;
    const float* Bp = proj + rowb * 96 + 64;
#pragma unroll
    for (int n = 0; n < N_; ++n) {
      float dA = __expf(dtv * Arow[n]);
      h[n] = dA * h[n] + dtx * Bp[n];
      ac[n] *= dA;
    }
  }
  size_t sb = ((((size_t)b << 10) + d) << 10) + (c << 4);
#pragma unroll
  for (int n = 0; n < N_; ++n) { acum[sb + n] = ac[n]; hloc[sb + n] = h[n]; }
}

__global__ __launch_bounds__(256) void scan_p2_k(
    const float* __restrict__ acum, const float* __restrict__ hloc, float* __restrict__ hin)
{
  int idx = blockIdx.x * 256 + threadIdx.x;  // B*1024*16
  int n = idx & 15;
  int dn = idx >> 4;
  size_t base = ((size_t)dn << 10) + n;
  float hs = 0.0f;
  for (int c = 0; c < NC_; ++c) {
    hin[base + (c << 4)] = hs;
    hs = acum[base + (c << 4)] * hs + hloc[base + (c << 4)];
  }
}

__global__ __launch_bounds__(256) void scan_p3_k(
    const u16* __restrict__ dt, const u16* __restrict__ xc, const float* __restrict__ proj,
    const float* __restrict__ A_log, const float* __restrict__ Dp, const float* __restrict__ hin,
    const u16* __restrict__ xz, u16* __restrict__ yg)
{
  int c = blockIdx.x & (NC_ - 1);
  int q = (blockIdx.x >> 6) & 3;
  int b = blockIdx.x >> 8;
  int d = (q << 8) + threadIdx.x;
  float Arow[N_];
#pragma unroll
  for (int n = 0; n < N_; ++n) Arow[n] = -__expf(A_log[(d << 4) + n]);
  float h[N_];
  size_t sb = ((((size_t)b << 10) + d) << 10) + (c << 4);
#pragma unroll
  for (int n = 0; n < N_; ++n) h[n] = hin[sb + n];
  float Dv = Dp[d];
  int l0 = c << 6;
  for (int i = 0; i < LC_; ++i) {
    size_t rowb = (size_t)b * L_ + (l0 + i);
    float dtv = bf2f(dt[(rowb << 10) + d]);
    float xv = bf2f(xc[(rowb << 10) + d]);
    float dtx = dtv * xv;
    const float* Bp = proj + rowb * 96 + 64;
    const float* Cp = proj + rowb * 96 + 80;
    float y = 0.0f;
#pragma unroll
    for (int n = 0; n < N_; ++n) {
      float dA = __expf(dtv * Arow[n]);
      h[n] = dA * h[n] + dtx * Bp[n];
      y += h[n] * Cp[n];
    }
    y += Dv * xv;
    float zv = bf2f(xz[(rowb << 11) + 1024 + d]);
    yg[(rowb << 10) + d] = f2bf(y * zv * sigmoidf_(zv));
  }
}

// ---------------- driver ---------------------------------------------------
extern "C" void kernel_launch(void* const* d_in, const int* in_sizes, int n_in,
                              void* d_out, int out_size, void* d_ws, size_t ws_size,
                              hipStream_t stream)
{
  const float* x_in      = (const float*)d_in[0];
  const int*   path      = (const int*)d_in[1];
  const int*   path_rev  = (const int*)d_in[2];
  const float* in_proj_w = (const float*)d_in[3];
  const float* conv_w    = (const float*)d_in[4];
  const float* conv_b    = (const float*)d_in[5];
  const float* x_proj_w  = (const float*)d_in[6];
  const float* dt_proj_w = (const float*)d_in[7];
  const float* dt_proj_b = (const float*)d_in[8];
  const float* A_log     = (const float*)d_in[9];
  const float* Dp        = (const float*)d_in[10];
  const float* out_pw    = (const float*)d_in[11];
  const float* fc1_w     = (const float*)d_in[12];
  const float* fc1_b     = (const float*)d_in[13];
  const float* fc2_w     = (const float*)d_in[14];
  const float* fc2_b     = (const float*)d_in[15];
  float* out = (float*)d_out;

  char* w = (char*)d_ws;
  size_t off = 0;
  auto alloc = [&](size_t bytes) -> char* {
    char* p = w + off;
    off = (off + bytes + 255) & ~(size_t)255;
    return p;
  };
  u16*   wbf   = (u16*)  alloc((size_t)WBF_TOT * 2);     // bf16 weights (23 MB)
  u16*   ln_bf = (u16*)  alloc((size_t)BL_ * 1024 * 2);  // LN1 out; later LN2 out
  u16*   xz    = (u16*)  alloc((size_t)BL_ * 2048 * 2);  // bf16 xz; later mo (bf16)
  u16*   xc    = (u16*)  alloc((size_t)BL_ * 1024 * 2);
  char*  pool0 = alloc(0);
  float* proj  = (float*)alloc((size_t)BL_ * 96 * 4);    // 3 MB
  u16*   dtr   = (u16*)  alloc((size_t)BL_ * 64 * 2);    // 1 MB
  u16*   dt    = (u16*)  alloc((size_t)BL_ * 1024 * 2);  // 16 MB
  float* acum  = (float*)alloc((size_t)2 * 1024 * NC_ * 16 * 4);  // 8 MB
  float* hloc  = (float*)alloc((size_t)2 * 1024 * NC_ * 16 * 4);  // 8 MB
  float* hin   = (float*)alloc((size_t)2 * 1024 * NC_ * 16 * 4);  // 8 MB
  u16*   yg    = (u16*)  alloc((size_t)BL_ * 1024 * 2);  // 16 MB  (pool total 60 MB)
  u16*   h1b   = (u16*)pool0;   // 64 MB, aliases dead pool (proj..yg) by fc1 time
  // xnew OUTSIDE h1b's 64 MB footprint:
  off = (size_t)(pool0 - w) + ((size_t)BL_ * 4096 * 2);
  u16*   xnew  = (u16*)  alloc((size_t)BL_ * 1024 * 2);  // 16 MB, bf16 residual
  u16*   mo    = xz;            // alias: z dead after scan_p3

  const u16* w_inp = wbf;
  const u16* w_xp  = wbf + 2097152;
  const u16* w_dtp = wbf + 2228224;
  const u16* w_op  = wbf + 2293760;
  const u16* w_fc1 = wbf + 3342336;
  const u16* w_fc2 = wbf + 7536640;

  dim3 blk(256);
  cvt_w_k<<<WBF_TOT / 256, blk, 0, stream>>>(in_proj_w, x_proj_w, dt_proj_w, out_pw,
                                             fc1_w, fc2_w, wbf);
  ln_gather_k<<<BL_, blk, 0, stream>>>(x_in, path, ln_bf);
  gemm_bt<M_BF16, 1024><<<dim3(16, 64), blk, 0, stream>>>(ln_bf, w_inp, nullptr, xz, nullptr, nullptr, 8192, 2048);
  conv_silu_k<<<(BL_ * 1024) / 256, blk, 0, stream>>>(xz, conv_w, conv_b, xc);
  gemm_bt<M_PROJ, 1024><<<dim3(1, 64), blk, 0, stream>>>(xc, w_xp, proj, dtr, nullptr, nullptr, 8192, 96);
  gemm_bt<M_SOFTPLUS, 64><<<dim3(8, 64), blk, 0, stream>>>(dtr, w_dtp, nullptr, dt, dt_proj_b, nullptr, 8192, 1024);
  scan_p1_k<<<2 * 4 * NC_, blk, 0, stream>>>(dt, xc, proj, A_log, acum, hloc);
  scan_p2_k<<<(2 * 1024 * 16) / 256, blk, 0, stream>>>(acum, hloc, hin);
  scan_p3_k<<<2 * 4 * NC_, blk, 0, stream>>>(dt, xc, proj, A_log, Dp, hin, xz, yg);
  gemm_bt<M_BF16, 1024><<<dim3(8, 64), blk, 0, stream>>>(yg, w_op, nullptr, mo, nullptr, nullptr, 8192, 1024);
  ln_scatter_k<<<BL_, blk, 0, stream>>>(x_in, path_rev, mo, xnew, ln_bf);
  gemm_bt<M_GELU, 1024><<<dim3(32, 64), blk, 0, stream>>>(ln_bf, w_fc1, nullptr, h1b, fc1_b, nullptr, 8192, 4096);
  gemm_bt<M_BIASRES, 4096><<<dim3(8, 64), blk, 0, stream>>>(h1b, w_fc2, out, nullptr, fc2_b, xnew, 8192, 1024);
}

// Round 8
// 613.963 us; speedup vs baseline: 2.6478x; 1.0166x over previous
//
#include <hip/hip_runtime.h>
#include <cstdint>
#include <cstddef>

typedef unsigned short u16;
typedef __bf16 bf16x8 __attribute__((ext_vector_type(8)));
typedef float f32x4 __attribute__((ext_vector_type(4)));

#define B_ 2
#define L_ 4096
#define D_ 1024
#define N_ 16
#define BL_ 8192
#define NC_ 64   /* scan chunks */
#define LC_ 64   /* steps per chunk */

__device__ __forceinline__ float bf2f(u16 h) {
  union { unsigned int u; float f; } v; v.u = ((unsigned int)h) << 16; return v.f;
}
__device__ __forceinline__ u16 f2bf(float f) {
  union { float f; unsigned int u; } v; v.f = f;
  unsigned int r = v.u + 0x7FFFu + ((v.u >> 16) & 1u);
  return (u16)(r >> 16);
}
__device__ __forceinline__ float sigmoidf_(float x) { return 1.0f / (1.0f + __expf(-x)); }

// ---- weight fp32->bf16 pre-conversion (x_proj padded to 128 rows) --------
#define WBF_TOT 11730944
__global__ __launch_bounds__(256) void cvt_w_k(
    const float* __restrict__ s0, const float* __restrict__ s1,
    const float* __restrict__ s2, const float* __restrict__ s3,
    const float* __restrict__ s4, const float* __restrict__ s5,
    u16* __restrict__ dst)
{
  int i = blockIdx.x * 256 + threadIdx.x;
  if (i >= WBF_TOT) return;
  float v;
  if (i < 2097152) v = s0[i];
  else if (i < 2228224) { int j = i - 2097152; v = (j < 98304) ? s1[j] : 0.0f; }
  else if (i < 2293760) v = s2[i - 2228224];
  else if (i < 3342336) v = s3[i - 2293760];
  else if (i < 7536640) v = s4[i - 3342336];
  else v = s5[i - 7536640];
  dst[i] = f2bf(v);
}

#define BK 32
enum { M_BF16 = 0, M_PROJ = 1, M_SOFTPLUS = 2, M_GELU = 3, M_BIASRES = 4 };

#define GLDS(gp, lp) __builtin_amdgcn_global_load_lds( \
    (const __attribute__((address_space(1))) void*)(gp), \
    (__attribute__((address_space(3))) void*)(lp), 16, 0, 0)

// Shared epilogue math
template<int MODE>
__device__ __forceinline__ void epi_store(
    float v, size_t row, int col, int Nn,
    float* __restrict__ C, u16* __restrict__ C2,
    const float* __restrict__ bias, const u16* __restrict__ resid)
{
  if constexpr (MODE == M_BF16) {
    C2[row * Nn + col] = f2bf(v);
  } else if constexpr (MODE == M_PROJ) {
    C[row * 96 + col] = v;
    if (col < 64) C2[(row << 6) + col] = f2bf(v);
  } else if constexpr (MODE == M_SOFTPLUS) {
    v += bias[col];
    v = (v > 20.0f) ? v : log1pf(__expf(v));
    C2[row * Nn + col] = f2bf(v);
  } else if constexpr (MODE == M_GELU) {
    v += bias[col];
    float a = 0.7978845608028654f * (v + 0.044715f * v * v * v);
    float t = 1.0f - 2.0f / (__expf(2.0f * a) + 1.0f);
    C2[row * Nn + col] = f2bf(0.5f * v * (1.0f + t));
  } else if constexpr (MODE == M_BIASRES) {
    C[row * Nn + col] = v + bias[col] + bf2f(resid[row * Nn + col]);
  }
}

// ---------------- gemm_bt: 128x128 tile, 64x64 wave (small GEMMs) ----------
#define BM 128
#define BN 128

template<int MODE, int K>
__global__ __launch_bounds__(256) void gemm_bt(
    const u16* __restrict__ A, const u16* __restrict__ W,
    float* __restrict__ C, u16* __restrict__ C2,
    const float* __restrict__ bias, const u16* __restrict__ resid,
    int M, int N)
{
  __shared__ __align__(16) u16 As[3][BM * BK];
  __shared__ __align__(16) u16 Bs[3][BN * BK];

  const int id = blockIdx.x + gridDim.x * blockIdx.y;
  const int xcd = id & 7;
  const int qq = id >> 3;
  const int bandH = gridDim.y >> 3;
  const int xs = qq % gridDim.x;
  const int ys = xcd * bandH + qq / gridDim.x;
  const int bm = ys * BM;
  const int bn = xs * BN;

  const int tid = threadIdx.x;
  const int lane = tid & 63;
  const int wave = tid >> 6;
  const int wr = (wave >> 1) * 64;
  const int wc = (wave & 1) * 64;

  f32x4 acc[4][4];
#pragma unroll
  for (int i = 0; i < 4; ++i)
#pragma unroll
    for (int j = 0; j < 4; ++j)
#pragma unroll
      for (int r = 0; r < 4; ++r) acc[i][j][r] = 0.0f;

  const int r0 = tid >> 2;
  const int ke = (((tid & 3) ^ (r0 & 3)) << 3);   // XOR bank swizzle (global side)
  const u16* Ab = A + (size_t)(bm + r0) * K + ke;
  const u16* Wb = W + (size_t)(bn + r0) * K + ke;
  constexpr size_t rstep = (size_t)64 * K;

  auto issue = [&](int buf, int k0) {
    GLDS(Ab + k0, &As[buf][tid * 8]);
    GLDS(Ab + k0 + rstep, &As[buf][(tid + 256) * 8]);
    GLDS(Wb + k0, &Bs[buf][tid * 8]);
    GLDS(Wb + k0 + rstep, &Bs[buf][(tid + 256) * 8]);
  };

  issue(0, 0);
  if constexpr (BK < K) issue(1, BK);

  const int mr = lane & 15;
  const int pos = (((lane >> 4) ^ (mr & 3)) << 3);
  constexpr int NIT = K / BK;

  auto step = [&](int it) {
    if (it + 1 < NIT) asm volatile("s_waitcnt vmcnt(4)" ::: "memory");
    else              asm volatile("s_waitcnt vmcnt(0)" ::: "memory");
    asm volatile("s_barrier" ::: "memory");
    if (it + 2 < NIT) issue((it + 2) % 3, (it + 2) * BK);
    const int cur = it % 3;
    bf16x8 af[4], bfr[4];
#pragma unroll
    for (int i = 0; i < 4; ++i)
      af[i] = *(const bf16x8*)(&As[cur][(wr + i * 16 + mr) * BK + pos]);
#pragma unroll
    for (int j = 0; j < 4; ++j)
      bfr[j] = *(const bf16x8*)(&Bs[cur][(wc + j * 16 + mr) * BK + pos]);
#pragma unroll
    for (int i = 0; i < 4; ++i)
#pragma unroll
      for (int j = 0; j < 4; ++j)
        acc[i][j] = __builtin_amdgcn_mfma_f32_16x16x32_bf16(af[i], bfr[j], acc[i][j], 0, 0, 0);
  };

  if constexpr (NIT <= 32) {
#pragma unroll
    for (int it = 0; it < NIT; ++it) step(it);
  } else {
#pragma unroll 6
    for (int it = 0; it < NIT; ++it) step(it);
  }

  const int mlo = (lane >> 4) << 2;
  const int nlo = lane & 15;
#pragma unroll
  for (int i = 0; i < 4; ++i) {
#pragma unroll
    for (int j = 0; j < 4; ++j) {
      int col = bn + wc + j * 16 + nlo;
      if (col < N) {
#pragma unroll
        for (int r = 0; r < 4; ++r) {
          size_t row = (size_t)(bm + wr + i * 16 + mlo + r);
          epi_store<MODE>(acc[i][j][r], row, col, N, C, C2, bias, resid);
        }
      }
    }
  }
}

// ---------------- gemm_big: 128x256 tile, 4 waves of 64x128 ----------------
// 12 b128 frag reads per 32 MFMAs (0.375 vs 0.5) -> -25% LDS traffic/FLOP;
// barriers/FLOP halve. 3-buf ring, wait vmcnt(6), 6 GLDS/thread/iter.
#define BM2 128
#define BN2 256

template<int MODE, int K>
__global__ __launch_bounds__(256, 2) void gemm_big(
    const u16* __restrict__ A, const u16* __restrict__ W,
    float* __restrict__ C, u16* __restrict__ C2,
    const float* __restrict__ bias, const u16* __restrict__ resid,
    int M, int N)
{
  __shared__ __align__(16) u16 As[3][BM2 * BK];   // 8 KB / buf
  __shared__ __align__(16) u16 Bs[3][BN2 * BK];   // 16 KB / buf

  const int id = blockIdx.x + gridDim.x * blockIdx.y;
  const int xcd = id & 7;
  const int qq = id >> 3;
  const int bandH = gridDim.y >> 3;
  const int xs = qq % gridDim.x;
  const int ys = xcd * bandH + qq / gridDim.x;
  const int bm = ys * BM2;
  const int bn = xs * BN2;

  const int tid = threadIdx.x;
  const int lane = tid & 63;
  const int wave = tid >> 6;
  const int wm = (wave >> 1) * 64;    // wave covers 64 rows x 128 cols
  const int wn = (wave & 1) * 128;

  f32x4 acc[4][8];
#pragma unroll
  for (int i = 0; i < 4; ++i)
#pragma unroll
    for (int j = 0; j < 8; ++j)
#pragma unroll
      for (int r = 0; r < 4; ++r) acc[i][j][r] = 0.0f;

  const int r0 = tid >> 2;
  const int ke = (((tid & 3) ^ (r0 & 3)) << 3);   // XOR bank swizzle
  const u16* Ab = A + (size_t)(bm + r0) * K + ke;
  const u16* Wb = W + (size_t)(bn + r0) * K + ke;
  constexpr size_t rstep = (size_t)64 * K;

  auto issue = [&](int buf, int k0) {
    GLDS(Ab + k0, &As[buf][tid * 8]);
    GLDS(Ab + k0 + rstep, &As[buf][(tid + 256) * 8]);
    GLDS(Wb + k0, &Bs[buf][tid * 8]);
    GLDS(Wb + k0 + rstep,     &Bs[buf][(tid + 256) * 8]);
    GLDS(Wb + k0 + 2 * rstep, &Bs[buf][(tid + 512) * 8]);
    GLDS(Wb + k0 + 3 * rstep, &Bs[buf][(tid + 768) * 8]);
  };

  issue(0, 0);
  issue(1, BK);

  const int mr = lane & 15;
  const int pos = (((lane >> 4) ^ (mr & 3)) << 3);
  constexpr int NIT = K / BK;

  auto step = [&](int it) {
    if (it + 1 < NIT) asm volatile("s_waitcnt vmcnt(6)" ::: "memory");
    else              asm volatile("s_waitcnt vmcnt(0)" ::: "memory");
    asm volatile("s_barrier" ::: "memory");
    if (it + 2 < NIT) issue((it + 2) % 3, (it + 2) * BK);
    const int cur = it % 3;
    bf16x8 af[4], bfr[8];
#pragma unroll
    for (int i = 0; i < 4; ++i)
      af[i] = *(const bf16x8*)(&As[cur][(wm + i * 16 + mr) * BK + pos]);
#pragma unroll
    for (int j = 0; j < 8; ++j)
      bfr[j] = *(const bf16x8*)(&Bs[cur][(wn + j * 16 + mr) * BK + pos]);
#pragma unroll
    for (int i = 0; i < 4; ++i)
#pragma unroll
      for (int j = 0; j < 8; ++j)
        acc[i][j] = __builtin_amdgcn_mfma_f32_16x16x32_bf16(af[i], bfr[j], acc[i][j], 0, 0, 0);
  };

  if constexpr (NIT <= 32) {
#pragma unroll
    for (int it = 0; it < NIT; ++it) step(it);
  } else {
#pragma unroll 6
    for (int it = 0; it < NIT; ++it) step(it);
  }

  const int mlo = (lane >> 4) << 2;
  const int nlo = lane & 15;
#pragma unroll
  for (int i = 0; i < 4; ++i) {
#pragma unroll
    for (int j = 0; j < 8; ++j) {
      int col = bn + wn + j * 16 + nlo;
#pragma unroll
      for (int r = 0; r < 4; ++r) {
        size_t row = (size_t)(bm + wm + i * 16 + mlo + r);
        epi_store<MODE>(acc[i][j][r], row, col, N, C, C2, bias, resid);
      }
    }
  }
}

// ---------------- LayerNorm helpers --------------------------------------
__device__ __forceinline__ void blockReduce2(float& s, float& q) {
#pragma unroll
  for (int o = 32; o > 0; o >>= 1) { s += __shfl_down(s, o, 64); q += __shfl_down(q, o, 64); }
  __shared__ float red[2][4];
  int lane = threadIdx.x & 63, wave = threadIdx.x >> 6;
  if (lane == 0) { red[0][wave] = s; red[1][wave] = q; }
  __syncthreads();
  s = red[0][0] + red[0][1] + red[0][2] + red[0][3];
  q = red[1][0] + red[1][1] + red[1][2] + red[1][3];
}

__global__ __launch_bounds__(256) void ln_gather_k(
    const float* __restrict__ x, const int* __restrict__ path, u16* __restrict__ out)
{
  int b = blockIdx.x >> 12;
  int l = blockIdx.x & 4095;
  int src = path[l];
  const float* row = x + (((size_t)b * L_ + src) << 10);
  u16* orow = out + (((size_t)b * L_ + l) << 10);
  float v[4], s = 0.f, q = 0.f;
#pragma unroll
  for (int i = 0; i < 4; ++i) {
    v[i] = row[threadIdx.x + (i << 8)];
    s += v[i]; q += v[i] * v[i];
  }
  blockReduce2(s, q);
  float mean = s * (1.0f / 1024.0f);
  float var = q * (1.0f / 1024.0f) - mean * mean;
  float rstd = rsqrtf(var + 1e-6f);
#pragma unroll
  for (int i = 0; i < 4; ++i)
    orow[threadIdx.x + (i << 8)] = f2bf((v[i] - mean) * rstd);
}

__global__ __launch_bounds__(256) void ln_scatter_k(
    const float* __restrict__ x, const int* __restrict__ prev,
    const u16* __restrict__ mo, u16* __restrict__ xnew, u16* __restrict__ lnout)
{
  int b = blockIdx.x >> 12;
  int l = blockIdx.x & 4095;
  int pl = prev[l];
  const float* xr = x + (((size_t)b * L_ + l) << 10);
  const u16* mr_ = mo + (((size_t)b * L_ + pl) << 10);
  size_t base = ((size_t)blockIdx.x) << 10;
  float v[4], s = 0.f, q = 0.f;
#pragma unroll
  for (int i = 0; i < 4; ++i) {
    v[i] = xr[threadIdx.x + (i << 8)] + bf2f(mr_[threadIdx.x + (i << 8)]);
    s += v[i]; q += v[i] * v[i];
  }
  blockReduce2(s, q);
  float mean = s * (1.0f / 1024.0f);
  float var = q * (1.0f / 1024.0f) - mean * mean;
  float rstd = rsqrtf(var + 1e-6f);
#pragma unroll
  for (int i = 0; i < 4; ++i) {
    xnew[base + threadIdx.x + (i << 8)] = f2bf(v[i]);
    lnout[base + threadIdx.x + (i << 8)] = f2bf((v[i] - mean) * rstd);
  }
}

__global__ __launch_bounds__(256) void conv_silu_k(
    const u16* __restrict__ xz, const float* __restrict__ cw, const float* __restrict__ cb,
    u16* __restrict__ xc)
{
  int idx = blockIdx.x * 256 + threadIdx.x;
  int d = idx & 1023;
  int l = (idx >> 10) & 4095;
  int b = idx >> 22;
  float acc = cb[d];
#pragma unroll
  for (int k = 0; k < 4; ++k) {
    int ls = l + k - 3;
    if (ls >= 0)
      acc += cw[(d << 2) + k] * bf2f(xz[(((size_t)b * L_ + ls) << 11) + d]);
  }
  acc = acc * sigmoidf_(acc);
  xc[idx] = f2bf(acc);
}

// ---------------- selective scan, 3-phase chunked -------------------------
__global__ __launch_bounds__(256) void scan_p1_k(
    const u16* __restrict__ dt, const u16* __restrict__ xc, const float* __restrict__ proj,
    const float* __restrict__ A_log, float* __restrict__ acum, float* __restrict__ hloc)
{
  int c = blockIdx.x & (NC_ - 1);
  int q = (blockIdx.x >> 6) & 3;
  int b = blockIdx.x >> 8;
  int d = (q << 8) + threadIdx.x;
  float Arow[N_];
#pragma unroll
  for (int n = 0; n < N_; ++n) Arow[n] = -__expf(A_log[(d << 4) + n]);
  float h[N_], ac[N_];
#pragma unroll
  for (int n = 0; n < N_; ++n) { h[n] = 0.0f; ac[n] = 1.0f; }
  int l0 = c << 6;
  for (int i = 0; i < LC_; ++i) {
    size_t rowb = (size_t)b * L_ + (l0 + i);
    float dtv = bf2f(dt[(rowb << 10) + d]);
    float xv = bf2f(xc[(rowb << 10) + d]);
    float dtx = dtv * xv;
    const float* Bp = proj + rowb * 96 + 64;
#pragma unroll
    for (int n = 0; n < N_; ++n) {
      float dA = __expf(dtv * Arow[n]);
      h[n] = dA * h[n] + dtx * Bp[n];
      ac[n] *= dA;
    }
  }
  size_t sb = ((((size_t)b << 10) + d) << 10) + (c << 4);
#pragma unroll
  for (int n = 0; n < N_; ++n) { acum[sb + n] = ac[n]; hloc[sb + n] = h[n]; }
}

__global__ __launch_bounds__(256) void scan_p2_k(
    const float* __restrict__ acum, const float* __restrict__ hloc, float* __restrict__ hin)
{
  int idx = blockIdx.x * 256 + threadIdx.x;
  int n = idx & 15;
  int dn = idx >> 4;
  size_t base = ((size_t)dn << 10) + n;
  float hs = 0.0f;
  for (int c = 0; c < NC_; ++c) {
    hin[base + (c << 4)] = hs;
    hs = acum[base + (c << 4)] * hs + hloc[base + (c << 4)];
  }
}

__global__ __launch_bounds__(256) void scan_p3_k(
    const u16* __restrict__ dt, const u16* __restrict__ xc, const float* __restrict__ proj,
    const float* __restrict__ A_log, const float* __restrict__ Dp, const float* __restrict__ hin,
    const u16* __restrict__ xz, u16* __restrict__ yg)
{
  int c = blockIdx.x & (NC_ - 1);
  int q = (blockIdx.x >> 6) & 3;
  int b = blockIdx.x >> 8;
  int d = (q << 8) + threadIdx.x;
  float Arow[N_];
#pragma unroll
  for (int n = 0; n < N_; ++n) Arow[n] = -__expf(A_log[(d << 4) + n]);
  float h[N_];
  size_t sb = ((((size_t)b << 10) + d) << 10) + (c << 4);
#pragma unroll
  for (int n = 0; n < N_; ++n) h[n] = hin[sb + n];
  float Dv = Dp[d];
  int l0 = c << 6;
  for (int i = 0; i < LC_; ++i) {
    size_t rowb = (size_t)b * L_ + (l0 + i);
    float dtv = bf2f(dt[(rowb << 10) + d]);
    float xv = bf2f(xc[(rowb << 10) + d]);
    float dtx = dtv * xv;
    const float* Bp = proj + rowb * 96 + 64;
    const float* Cp = proj + rowb * 96 + 80;
    float y = 0.0f;
#pragma unroll
    for (int n = 0; n < N_; ++n) {
      float dA = __expf(dtv * Arow[n]);
      h[n] = dA * h[n] + dtx * Bp[n];
      y += h[n] * Cp[n];
    }
    y += Dv * xv;
    float zv = bf2f(xz[(rowb << 11) + 1024 + d]);
    yg[(rowb << 10) + d] = f2bf(y * zv * sigmoidf_(zv));
  }
}

// ---------------- driver ---------------------------------------------------
extern "C" void kernel_launch(void* const* d_in, const int* in_sizes, int n_in,
                              void* d_out, int out_size, void* d_ws, size_t ws_size,
                              hipStream_t stream)
{
  const float* x_in      = (const float*)d_in[0];
  const int*   path      = (const int*)d_in[1];
  const int*   path_rev  = (const int*)d_in[2];
  const float* in_proj_w = (const float*)d_in[3];
  const float* conv_w    = (const float*)d_in[4];
  const float* conv_b    = (const float*)d_in[5];
  const float* x_proj_w  = (const float*)d_in[6];
  const float* dt_proj_w = (const float*)d_in[7];
  const float* dt_proj_b = (const float*)d_in[8];
  const float* A_log     = (const float*)d_in[9];
  const float* Dp        = (const float*)d_in[10];
  const float* out_pw    = (const float*)d_in[11];
  const float* fc1_w     = (const float*)d_in[12];
  const float* fc1_b     = (const float*)d_in[13];
  const float* fc2_w     = (const float*)d_in[14];
  const float* fc2_b     = (const float*)d_in[15];
  float* out = (float*)d_out;

  char* w = (char*)d_ws;
  size_t off = 0;
  auto alloc = [&](size_t bytes) -> char* {
    char* p = w + off;
    off = (off + bytes + 255) & ~(size_t)255;
    return p;
  };
  u16*   wbf   = (u16*)  alloc((size_t)WBF_TOT * 2);
  u16*   ln_bf = (u16*)  alloc((size_t)BL_ * 1024 * 2);
  u16*   xz    = (u16*)  alloc((size_t)BL_ * 2048 * 2);
  u16*   xc    = (u16*)  alloc((size_t)BL_ * 1024 * 2);
  char*  pool0 = alloc(0);
  float* proj  = (float*)alloc((size_t)BL_ * 96 * 4);
  u16*   dtr   = (u16*)  alloc((size_t)BL_ * 64 * 2);
  u16*   dt    = (u16*)  alloc((size_t)BL_ * 1024 * 2);
  float* acum  = (float*)alloc((size_t)2 * 1024 * NC_ * 16 * 4);
  float* hloc  = (float*)alloc((size_t)2 * 1024 * NC_ * 16 * 4);
  float* hin   = (float*)alloc((size_t)2 * 1024 * NC_ * 16 * 4);
  u16*   yg    = (u16*)  alloc((size_t)BL_ * 1024 * 2);
  u16*   h1b   = (u16*)pool0;   // 64 MB, aliases dead pool by fc1 time
  off = (size_t)(pool0 - w) + ((size_t)BL_ * 4096 * 2);
  u16*   xnew  = (u16*)  alloc((size_t)BL_ * 1024 * 2);
  u16*   mo    = xz;            // alias: z dead after scan_p3

  const u16* w_inp = wbf;
  const u16* w_xp  = wbf + 2097152;
  const u16* w_dtp = wbf + 2228224;
  const u16* w_op  = wbf + 2293760;
  const u16* w_fc1 = wbf + 3342336;
  const u16* w_fc2 = wbf + 7536640;

  dim3 blk(256);
  cvt_w_k<<<WBF_TOT / 256, blk, 0, stream>>>(in_proj_w, x_proj_w, dt_proj_w, out_pw,
                                             fc1_w, fc2_w, wbf);
  ln_gather_k<<<BL_, blk, 0, stream>>>(x_in, path, ln_bf);
  gemm_big<M_BF16, 1024><<<dim3(8, 64), blk, 0, stream>>>(ln_bf, w_inp, nullptr, xz, nullptr, nullptr, 8192, 2048);
  conv_silu_k<<<(BL_ * 1024) / 256, blk, 0, stream>>>(xz, conv_w, conv_b, xc);
  gemm_bt<M_PROJ, 1024><<<dim3(1, 64), blk, 0, stream>>>(xc, w_xp, proj, dtr, nullptr, nullptr, 8192, 96);
  gemm_bt<M_SOFTPLUS, 64><<<dim3(8, 64), blk, 0, stream>>>(dtr, w_dtp, nullptr, dt, dt_proj_b, nullptr, 8192, 1024);
  scan_p1_k<<<2 * 4 * NC_, blk, 0, stream>>>(dt, xc, proj, A_log, acum, hloc);
  scan_p2_k<<<(2 * 1024 * 16) / 256, blk, 0, stream>>>(acum, hloc, hin);
  scan_p3_k<<<2 * 4 * NC_, blk, 0, stream>>>(dt, xc, proj, A_log, Dp, hin, xz, yg);
  gemm_big<M_BF16, 1024><<<dim3(4, 64), blk, 0, stream>>>(yg, w_op, nullptr, mo, nullptr, nullptr, 8192, 1024);
  ln_scatter_k<<<BL_, blk, 0, stream>>>(x_in, path_rev, mo, xnew, ln_bf);
  gemm_big<M_GELU, 1024><<<dim3(16, 64), blk, 0, stream>>>(ln_bf, w_fc1, nullptr, h1b, fc1_b, nullptr, 8192, 4096);
  gemm_big<M_BIASRES, 4096><<<dim3(4, 64), blk, 0, stream>>>(h1b, w_fc2, out, nullptr, fc2_b, xnew, 8192, 1024);
}